// Round 9
// baseline (185.347 us; speedup 1.0000x reference)
//
#include <hip/hip_runtime.h>

#define Bb 4
#define Ll 256
#define NEG 0.2f

typedef __attribute__((ext_vector_type(8))) short short8;
typedef __attribute__((ext_vector_type(4))) float f32x4;
typedef __attribute__((ext_vector_type(4))) unsigned uint4v;

__device__ __forceinline__ float lrelu(float x) { return x >= 0.f ? x : NEG * x; }

__device__ __forceinline__ short f2bf(float x) {
  unsigned u = __builtin_bit_cast(unsigned, x);
  unsigned r = (u + 0x7FFFu + ((u >> 16) & 1u)) >> 16;
  return (short)r;
}

// pack two f32 -> u32 of 2 bf16 (round half up); elem0 in low 16
__device__ __forceinline__ unsigned pack2bf(float e, float o) {
  unsigned ue = __builtin_bit_cast(unsigned, e);
  unsigned uo = __builtin_bit_cast(unsigned, o);
  return ((ue + 0x8000u) >> 16) | ((uo + 0x8000u) & 0xFFFF0000u);
}

__device__ __forceinline__ float bflo(unsigned u) {
  return __builtin_bit_cast(float, u << 16);
}
__device__ __forceinline__ float bfhi(unsigned u) {
  return __builtin_bit_cast(float, u & 0xFFFF0000u);
}

// ---------------- merged prep: blocks 0..127 -> Gt (linear bf16 [n][k]);
// block 128 -> Vbf (bf16 [16][128], rows 8..15 zero), ch(8), c0(128) ----------------
__global__ void prep_kernel(const float* We_w, const float* We_b, const float* attn_w,
                            const float* We2_w, const float* We2_b, const float* edge_w,
                            const float* edge_b, const float* out_e_w, const float* out_e_b,
                            short* Vbf, float* chg, float* c0g, short* Gt) {
  int blk = blockIdx.x;
  int t = threadIdx.x; // 128 threads
  if (blk < 128) {
    __shared__ float m2[128];
    int c = blk; // k index
    int h = t >> 4, e = t & 15;
    float s = 0.f;
    for (int d = 0; d < 16; ++d) s += We2_w[c * 128 + h * 16 + d] * edge_w[d * 16 + e];
    m2[t] = s;
    __syncthreads();
    float g = 0.f;
    for (int f = 0; f < 128; ++f) g += m2[f] * out_e_w[f * 128 + t];
    Gt[t * 128 + c] = f2bf(g);
  } else {
    __shared__ float b2e[128];
    const float* we = attn_w + 64;
    for (int idx = t; idx < 1024; idx += 128) {
      int c = idx >> 3, h = idx & 7;
      float s = 0.f;
      for (int d = 0; d < 16; ++d) s += We_w[c * 128 + h * 16 + d] * we[d];
      Vbf[h * 128 + c] = f2bf(s);
      Vbf[(h + 8) * 128 + c] = 0;
    }
    if (t < 8) {
      float s = 0.f;
      for (int d = 0; d < 16; ++d) s += We_b[t * 16 + d] * we[d];
      chg[t] = s;
    }
    {
      int h = t >> 4, e = t & 15;
      float s = 0.f;
      for (int d = 0; d < 16; ++d) s += We2_b[h * 16 + d] * edge_w[d * 16 + e];
      b2e[t] = s + edge_b[e];
    }
    __syncthreads();
    float s = out_e_b[t];
    for (int f = 0; f < 128; ++f) s += b2e[f] * out_e_w[f * 128 + t];
    c0g[t] = s;
  }
}

// ---------------- pass 1 v3 (m97-style): persistent blocks, global_load_lds staging,
// swizzled LDS, dbuf; T = edge@G (bf16 frag-linear) + se.
// 1024 blocks x 8 tiles of 32 rows. Wave (wm,wn): rows wm*16+, cols wn*64+.
#define TPB_T 8
__global__ __launch_bounds__(256, 3) void edge_t_kernel(
    const float* __restrict__ edge, const short* __restrict__ Gt,
    const short* __restrict__ Vbf, const float* __restrict__ chg,
    short* __restrict__ Tf, float* __restrict__ seg) {
  __shared__ __align__(16) float abuf[2][32 * 128]; // 2 x 16 KB fp32, row-swizzled image
  int t = threadIdx.x;
  int l = t & 63, wid = t >> 6;
  int wm = wid >> 1, wn = wid & 1;
  int lc = l & 15, lq = l >> 4;

  // B fragments (Gt) and V fragments in registers, once per block
  short8 bv[4][4]; // [ks][nf], cols wn*64+nf*16+lc
#pragma unroll
  for (int ks = 0; ks < 4; ++ks)
#pragma unroll
    for (int nf = 0; nf < 4; ++nf)
      bv[ks][nf] = *(const short8*)(Gt + (wn * 64 + nf * 16 + lc) * 128 + ks * 32 + lq * 8);
  short8 vb[4];
#pragma unroll
  for (int ks = 0; ks < 4; ++ks) vb[ks] = *(const short8*)(Vbf + lc * 128 + ks * 32 + lq * 8);

  long tile0 = (long)blockIdx.x * TPB_T;
  int wuni = (t >> 6); // wave id (uniform within wave)

  // stage one 32x128 fp32 tile into swizzled LDS image via global_load_lds(16B)
  auto stage = [&](int buf, long tile) {
#pragma unroll
    for (int q = 0; q < 4; ++q) {
      int L = q * 256 + t;       // 16B chunk index 0..1023
      int row = L >> 5, c4 = L & 31;
      // source column pre-swizzled so linear LDS write yields swizzled image
      int scol = (c4 * 4) ^ ((row & 7) << 2); // float index within row
      const float* gp = edge + (tile * 32 + row) * 128 + scol;
      char* lp = (char*)abuf[buf] + q * 4096 + wuni * 1024;
      __builtin_amdgcn_global_load_lds(
          (const __attribute__((address_space(1))) unsigned*)gp,
          (__attribute__((address_space(3))) unsigned*)lp, 16, 0, 0);
    }
  };

  stage(0, tile0);
  __syncthreads();

  int cur = 0;
  for (int tt = 0; tt < TPB_T; ++tt) {
    long tile = tile0 + tt;
    if (tt + 1 < TPB_T) stage(cur ^ 1, tile + 1);

    const char* base = (const char*)abuf[cur];
    int row = wm * 16 + lc;
    int sw = (row & 7) << 4;
    const char* rbase = base + row * 512;

    f32x4 accT[4];
#pragma unroll
    for (int nf = 0; nf < 4; ++nf) accT[nf] = (f32x4){0.f, 0.f, 0.f, 0.f};
    f32x4 accS = (f32x4){0.f, 0.f, 0.f, 0.f};

#pragma unroll
    for (int ks = 0; ks < 4; ++ks) {
      int cb = ks * 128 + lq * 32;
      float4 f0 = *(const float4*)(rbase + (cb ^ sw));
      float4 f1 = *(const float4*)(rbase + ((cb + 16) ^ sw));
      uint4v u;
      u.x = pack2bf(f0.x, f0.y);
      u.y = pack2bf(f0.z, f0.w);
      u.z = pack2bf(f1.x, f1.y);
      u.w = pack2bf(f1.z, f1.w);
      short8 av = __builtin_bit_cast(short8, u);
#pragma unroll
      for (int nf = 0; nf < 4; ++nf)
        accT[nf] = __builtin_amdgcn_mfma_f32_16x16x32_bf16(bv[ks][nf], av, accT[nf], 0, 0, 0);
      if (wn == 0)
        accS = __builtin_amdgcn_mfma_f32_16x16x32_bf16(vb[ks], av, accS, 0, 0, 0);
    }

    // T store: frag-linear [tile][wid][np][lane] 16B chunks, fully coalesced
    {
      short* tb = Tf + tile * 4096 + wid * 1024 + l * 8;
      uint4v u0, u1;
      u0.x = pack2bf(accT[0].x, accT[0].y);
      u0.y = pack2bf(accT[0].z, accT[0].w);
      u0.z = pack2bf(accT[1].x, accT[1].y);
      u0.w = pack2bf(accT[1].z, accT[1].w);
      u1.x = pack2bf(accT[2].x, accT[2].y);
      u1.y = pack2bf(accT[2].z, accT[2].w);
      u1.z = pack2bf(accT[3].x, accT[3].y);
      u1.w = pack2bf(accT[3].z, accT[3].w);
      *(uint4v*)tb = u0;
      *(uint4v*)(tb + 512) = u1;
    }

    // se store: heads lq*4+r valid for lq<2
    if (wn == 0 && lq < 2) {
      f32x4 chv = *(const f32x4*)(chg + lq * 4);
      long slab = tile >> 3;
      int lrow = (int)(tile & 7) * 32 + wm * 16 + lc;
      f32x4 v = accS + chv;
      *(f32x4*)(seg + slab * 2048 + lrow * 8 + lq * 4) = v;
    }

    __syncthreads();
    cur ^= 1;
  }
}

// ---------------- node_in_fused: node_p = node@Wn + b; Whh; si; sj ----------------
__global__ __launch_bounds__(256) void node_in_fused(
    const float* __restrict__ node, const float* __restrict__ Wn_w,
    const float* __restrict__ Wn_b, const float* __restrict__ Wh_w,
    const float* __restrict__ Wh_b, const float* __restrict__ attn_w,
    float* __restrict__ node_p, float* __restrict__ Whh, float* __restrict__ si,
    float* __restrict__ sj) {
  __shared__ float a[4][256];
  __shared__ float np[4][256];
  int t = threadIdx.x;
  int row0 = blockIdx.x * 4;
  for (int q = t; q < 1024; q += 256) a[q >> 8][q & 255] = node[(long)row0 * 256 + q];
  __syncthreads();
  float acc[4];
  float bvv = Wn_b[t];
#pragma unroll
  for (int r = 0; r < 4; ++r) acc[r] = bvv;
  for (int k = 0; k < 256; ++k) {
    float w = Wn_w[k * 256 + t];
#pragma unroll
    for (int r = 0; r < 4; ++r) acc[r] += a[r][k] * w;
  }
#pragma unroll
  for (int r = 0; r < 4; ++r) {
    node_p[(long)(row0 + r) * 256 + t] = acc[r];
    np[r][t] = acc[r];
  }
  __syncthreads();
  int h = t >> 5, e = t & 31;
  float wb2 = Wh_b[e];
#pragma unroll
  for (int r = 0; r < 4; ++r) {
    float s = wb2;
    for (int d = 0; d < 32; ++d) s += np[r][h * 32 + d] * Wh_w[d * 32 + e];
    Whh[(long)(row0 + r) * 256 + t] = s;
  }
  if (t < 64) {
    int r = t >> 4, idx = t & 15, hh = idx & 7;
    const float* w = attn_w + (idx < 8 ? 0 : 32);
    float s = 0.f;
    for (int d = 0; d < 32; ++d) s += np[r][hh * 32 + d] * w[d];
    ((idx < 8) ? si : sj)[(long)(row0 + r) * 8 + hh] = s;
  }
}

// ---------------- attn v5: softmax + agg from precomputed seg ----------------
__global__ __launch_bounds__(256) void attn_fused(
    const float* __restrict__ node_p, const float* __restrict__ Whh,
    const float* __restrict__ si, const float* __restrict__ sj,
    const float* __restrict__ seg, float* __restrict__ node_h) {
  __shared__ float sjl[2048];
  __shared__ float sel[2048];
  __shared__ float pl[2048];
  __shared__ float sil[8];
  int t = threadIdx.x, bi = blockIdx.x;
  int b = bi >> 8, i = bi & 255;
  for (int q = t; q < 2048; q += 256) sjl[q] = sj[(long)b * 2048 + q];
  for (int q = t; q < 2048; q += 256) sel[q] = seg[(long)bi * 2048 + q];
  if (t < 8) sil[t] = si[(long)bi * 8 + t];
  __syncthreads();

  int g = t >> 5, l32 = t & 31;
  float sc[8];
  float mx = -1e30f;
#pragma unroll
  for (int m = 0; m < 8; ++m) {
    int k = l32 + 32 * m;
    float v = -1e30f;
    if (k < 255) {
      int jj = k + (k >= i ? 1 : 0);
      v = sil[g] + sjl[jj * 8 + g] + sel[jj * 8 + g];
      v = lrelu(v);
    }
    sc[m] = v;
    mx = fmaxf(mx, v);
  }
#pragma unroll
  for (int d = 16; d >= 1; d >>= 1) mx = fmaxf(mx, __shfl_xor(mx, d));
  float sum = 0.f;
#pragma unroll
  for (int m = 0; m < 8; ++m) {
    int k = l32 + 32 * m;
    float e = (k < 255) ? __expf(sc[m] - mx) : 0.f;
    sc[m] = e;
    sum += e;
  }
#pragma unroll
  for (int d = 16; d >= 1; d >>= 1) sum += __shfl_xor(sum, d);
  float inv = 1.f / sum;
#pragma unroll
  for (int m = 0; m < 8; ++m) {
    int k = l32 + 32 * m;
    if (k < 255) pl[k * 8 + g] = sc[m] * inv;
  }
  __syncthreads();

  int h = g;
  const float* wb = Whh + (long)b * 65536 + t;
  float acc0 = 0.f, acc1 = 0.f;
#pragma unroll 8
  for (int j = 0; j < 256; j += 2) {
    int k0 = (j == 0) ? 254 : (j - 1);
    int k1 = j;
    float w0 = (j == i) ? 0.f : pl[k0 * 8 + h];
    float w1 = (j + 1 == i) ? 0.f : pl[k1 * 8 + h];
    acc0 += w0 * wb[(long)j * 256];
    acc1 += w1 * wb[(long)(j + 1) * 256];
  }
  float acc = acc0 + acc1;
  float np = node_p[(long)bi * 256 + t];
  node_h[(long)bi * 256 + t] = np + lrelu(acc);
}

// ---------------- attn fallback (computes se from fp32 edge) ----------------
__global__ __launch_bounds__(256) void attn_fallback(
    const float* __restrict__ node_p, const float* __restrict__ Whh,
    const float* __restrict__ si, const float* __restrict__ sj,
    const float* __restrict__ edge, const short* __restrict__ Vbf,
    const float* __restrict__ chg, float* __restrict__ node_h) {
  __shared__ float sjl[2048];
  __shared__ float sel[2048];
  __shared__ float pl[2048];
  __shared__ float sil[8];
  int t = threadIdx.x, bi = blockIdx.x;
  int b = bi >> 8, i = bi & 255;
  for (int q = t; q < 2048; q += 256) sjl[q] = sj[(long)b * 2048 + q];
  if (t < 8) sil[t] = si[(long)bi * 8 + t];
  {
    int l = t & 63, w = t >> 6;
    int lc = l & 15, lq = l >> 4;
    short8 vb[4];
#pragma unroll
    for (int ks = 0; ks < 4; ++ks) vb[ks] = *(const short8*)(Vbf + lc * 128 + ks * 32 + lq * 8);
    f32x4 acc[4];
#pragma unroll
    for (int mf = 0; mf < 4; ++mf) acc[mf] = (f32x4){0.f, 0.f, 0.f, 0.f};
#pragma unroll
    for (int mf = 0; mf < 4; ++mf) {
      int row = w * 64 + mf * 16 + lc;
#pragma unroll
      for (int ks = 0; ks < 4; ++ks) {
        const float* ap = edge + (long)bi * 32768 + row * 128 + ks * 32 + lq * 8;
        float4 f0 = *(const float4*)ap;
        float4 f1 = *(const float4*)(ap + 4);
        uint4v u;
        u.x = pack2bf(f0.x, f0.y);
        u.y = pack2bf(f0.z, f0.w);
        u.z = pack2bf(f1.x, f1.y);
        u.w = pack2bf(f1.z, f1.w);
        acc[mf] = __builtin_amdgcn_mfma_f32_16x16x32_bf16(vb[ks], __builtin_bit_cast(short8, u),
                                                          acc[mf], 0, 0, 0);
      }
    }
    if (lq < 2) {
      f32x4 chv = *(const f32x4*)(chg + lq * 4);
#pragma unroll
      for (int mf = 0; mf < 4; ++mf) {
        int row = w * 64 + mf * 16 + lc;
        f32x4 v = acc[mf] + chv;
        *(f32x4*)(&sel[row * 8 + lq * 4]) = v;
      }
    }
  }
  __syncthreads();
  int g = t >> 5, l32 = t & 31;
  float sc[8];
  float mx = -1e30f;
#pragma unroll
  for (int m = 0; m < 8; ++m) {
    int k = l32 + 32 * m;
    float v = -1e30f;
    if (k < 255) {
      int jj = k + (k >= i ? 1 : 0);
      v = sil[g] + sjl[jj * 8 + g] + sel[jj * 8 + g];
      v = lrelu(v);
    }
    sc[m] = v;
    mx = fmaxf(mx, v);
  }
#pragma unroll
  for (int d = 16; d >= 1; d >>= 1) mx = fmaxf(mx, __shfl_xor(mx, d));
  float sum = 0.f;
#pragma unroll
  for (int m = 0; m < 8; ++m) {
    int k = l32 + 32 * m;
    float e = (k < 255) ? __expf(sc[m] - mx) : 0.f;
    sc[m] = e;
    sum += e;
  }
#pragma unroll
  for (int d = 16; d >= 1; d >>= 1) sum += __shfl_xor(sum, d);
  float inv = 1.f / sum;
#pragma unroll
  for (int m = 0; m < 8; ++m) {
    int k = l32 + 32 * m;
    if (k < 255) pl[k * 8 + g] = sc[m] * inv;
  }
  __syncthreads();
  int h = g;
  const float* wb = Whh + (long)b * 65536 + t;
  float acc0 = 0.f, acc1 = 0.f;
#pragma unroll 8
  for (int j = 0; j < 256; j += 2) {
    int k0 = (j == 0) ? 254 : (j - 1);
    int k1 = j;
    float w0 = (j == i) ? 0.f : pl[k0 * 8 + h];
    float w1 = (j + 1 == i) ? 0.f : pl[k1 * 8 + h];
    acc0 += w0 * wb[(long)j * 256];
    acc1 += w1 * wb[(long)(j + 1) * 256];
  }
  float acc = acc0 + acc1;
  float np = node_p[(long)bi * 256 + t];
  node_h[(long)bi * 256 + t] = np + lrelu(acc);
}

// ---------------- node_out_pq: out_node; node_p2; P/Q ----------------
__global__ __launch_bounds__(256) void node_out_pq(
    const float* __restrict__ node_h, const float* __restrict__ out_n_w,
    const float* __restrict__ out_n_b, const float* __restrict__ Wn2_w,
    const float* __restrict__ Wn2_b, const float* __restrict__ edge_w,
    const float* __restrict__ out_e_w, float* __restrict__ out_node,
    float* __restrict__ Pg, float* __restrict__ Qg) {
  __shared__ float a[4][256];
  __shared__ float b2[4][256];
  __shared__ float ninj[4][256];
  int t = threadIdx.x;
  int row0 = blockIdx.x * 4;
  for (int q = t; q < 1024; q += 256) a[q >> 8][q & 255] = node_h[(long)row0 * 256 + q];
  __syncthreads();
  float acc[4];
  float bv1 = out_n_b[t];
#pragma unroll
  for (int r = 0; r < 4; ++r) acc[r] = bv1;
  for (int k = 0; k < 256; ++k) {
    float w = out_n_w[k * 256 + t];
#pragma unroll
    for (int r = 0; r < 4; ++r) acc[r] += a[r][k] * w;
  }
#pragma unroll
  for (int r = 0; r < 4; ++r) {
    out_node[(long)(row0 + r) * 256 + t] = acc[r];
    b2[r][t] = acc[r];
  }
  __syncthreads();
  float acc2[4];
  float bv2 = Wn2_b[t];
#pragma unroll
  for (int r = 0; r < 4; ++r) acc2[r] = bv2;
  for (int k = 0; k < 256; ++k) {
    float w = Wn2_w[k * 256 + t];
#pragma unroll
    for (int r = 0; r < 4; ++r) acc2[r] += b2[r][k] * w;
  }
#pragma unroll
  for (int r = 0; r < 4; ++r) a[r][t] = acc2[r]; // node_p2
  __syncthreads();
  {
    int f = t & 127, h = f >> 4, e = f & 15;
    const float* w = edge_w + 256 + (t >> 7) * 512; // w_i / w_j
#pragma unroll
    for (int r = 0; r < 4; ++r) {
      float s = 0.f;
      for (int d = 0; d < 32; ++d) s += a[r][h * 32 + d] * w[d * 16 + e];
      ninj[r][t] = s;
    }
  }
  __syncthreads();
  {
    int o = t & 127;
    int half = (t >> 7) * 128;
#pragma unroll
    for (int r = 0; r < 4; ++r) {
      float s = 0.f;
      const float* src = ninj[r] + half;
      for (int f = 0; f < 128; ++f) s += src[f] * out_e_w[f * 128 + o];
      ((t < 128) ? Pg : Qg)[(long)(row0 + r) * 128 + o] = s;
    }
  }
}

// ---------------- final: out_edge = T + P_i + Q_j + c0 (diag: oeb), streaming -------
// 2048 blocks x 128 rows = 4 subtiles of 32; matches edge_t v3 Tf layout.
__global__ __launch_bounds__(256) void edge_final_kernel(
    const short* __restrict__ Tf, const float* __restrict__ Pg,
    const float* __restrict__ Qg, const float* __restrict__ c0g,
    const float* __restrict__ oeb, float* __restrict__ out_edge) {
  int t = threadIdx.x;
  int l = t & 63, wid = t >> 6;
  int wm = wid >> 1, wn = wid & 1;
  int lc = l & 15, lq = l >> 4;
  long row0 = (long)blockIdx.x * 128;
  int b = (int)(row0 >> 16);
  int i = (int)((row0 >> 8) & 255);
  int j0 = (int)(row0 & 255);

  f32x4 pc[4];
#pragma unroll
  for (int nf = 0; nf < 4; ++nf) {
    int cb = wn * 64 + nf * 16 + lq * 4;
    f32x4 p = *(const f32x4*)(Pg + ((long)(b * 256 + i)) * 128 + cb);
    f32x4 c0 = *(const f32x4*)(c0g + cb);
    pc[nf] = p + c0;
  }

#pragma unroll
  for (int st = 0; st < 4; ++st) {
    long tile = blockIdx.x * 4 + st;
    const short* tb = Tf + tile * 4096 + wid * 1024 + l * 8;
    uint4v u0 = *(const uint4v*)tb;
    uint4v u1 = *(const uint4v*)(tb + 512);

    int er = st * 32 + wm * 16 + lc;
    int j = j0 + er;
    const float* Qrow = Qg + ((long)(b * 256 + j)) * 128;
    float* orow = out_edge + (row0 + er) * 128;
    if (j == i) {
#pragma unroll
      for (int nf = 0; nf < 4; ++nf) {
        int cb = wn * 64 + nf * 16 + lq * 4;
        *(f32x4*)(orow + cb) = *(const f32x4*)(oeb + cb);
      }
    } else {
      f32x4 v[4];
      v[0] = (f32x4){bflo(u0.x), bfhi(u0.x), bflo(u0.y), bfhi(u0.y)};
      v[1] = (f32x4){bflo(u0.z), bfhi(u0.z), bflo(u0.w), bfhi(u0.w)};
      v[2] = (f32x4){bflo(u1.x), bfhi(u1.x), bflo(u1.y), bfhi(u1.y)};
      v[3] = (f32x4){bflo(u1.z), bfhi(u1.z), bflo(u1.w), bfhi(u1.w)};
#pragma unroll
      for (int nf = 0; nf < 4; ++nf) {
        int cb = wn * 64 + nf * 16 + lq * 4;
        f32x4 q4 = *(const f32x4*)(Qrow + cb);
        *(f32x4*)(orow + cb) = v[nf] + pc[nf] + q4;
      }
    }
  }
}

// ---------------- fallback pass C (fp32 reads, MFMA, direct epilogue) ----------------
__global__ __launch_bounds__(256, 2) void edge_out_fallback(
    const float* __restrict__ edge, const short* __restrict__ Gt,
    const float* __restrict__ Pg, const float* __restrict__ Qg,
    const float* __restrict__ c0g, const float* __restrict__ oeb,
    float* __restrict__ out_edge) {
  int t = threadIdx.x;
  int l = t & 63, wid = t >> 6;
  int wm = wid >> 1, wn = wid & 1;
  int lc = l & 15, lq = l >> 4;
  long row0 = (long)blockIdx.x * 128;
  int b = (int)(row0 >> 16);
  int i = (int)((row0 >> 8) & 255);
  int j0 = (int)(row0 & 255);

  short8 bv[4][4];
#pragma unroll
  for (int ks = 0; ks < 4; ++ks)
#pragma unroll
    for (int nf = 0; nf < 4; ++nf)
      bv[ks][nf] = *(const short8*)(Gt + (wn * 64 + nf * 16 + lc) * 128 + ks * 32 + lq * 8);

  f32x4 acc[4][4];
#pragma unroll
  for (int mf = 0; mf < 4; ++mf)
#pragma unroll
    for (int nf = 0; nf < 4; ++nf) acc[mf][nf] = (f32x4){0.f, 0.f, 0.f, 0.f};

#pragma unroll
  for (int ks = 0; ks < 4; ++ks) {
    short8 av[4];
#pragma unroll
    for (int mf = 0; mf < 4; ++mf) {
      const float* ap = edge + (row0 + wm * 64 + mf * 16 + lc) * 128 + ks * 32 + lq * 8;
      float4 f0 = *(const float4*)ap;
      float4 f1 = *(const float4*)(ap + 4);
      uint4v u;
      u.x = pack2bf(f0.x, f0.y);
      u.y = pack2bf(f0.z, f0.w);
      u.z = pack2bf(f1.x, f1.y);
      u.w = pack2bf(f1.z, f1.w);
      av[mf] = __builtin_bit_cast(short8, u);
    }
#pragma unroll
    for (int mf = 0; mf < 4; ++mf)
#pragma unroll
      for (int nf = 0; nf < 4; ++nf)
        acc[mf][nf] =
            __builtin_amdgcn_mfma_f32_16x16x32_bf16(bv[ks][nf], av[mf], acc[mf][nf], 0, 0, 0);
  }

  f32x4 pc[4];
#pragma unroll
  for (int nf = 0; nf < 4; ++nf) {
    int cb = wn * 64 + nf * 16 + lq * 4;
    f32x4 p = *(const f32x4*)(Pg + ((long)(b * 256 + i)) * 128 + cb);
    f32x4 c0 = *(const f32x4*)(c0g + cb);
    pc[nf] = p + c0;
  }
#pragma unroll
  for (int mf = 0; mf < 4; ++mf) {
    int er = wm * 64 + mf * 16 + lc;
    int j = j0 + er;
    const float* Qrow = Qg + ((long)(b * 256 + j)) * 128;
    float* orow = out_edge + (row0 + er) * 128;
    if (j == i) {
#pragma unroll
      for (int nf = 0; nf < 4; ++nf) {
        int cb = wn * 64 + nf * 16 + lq * 4;
        *(f32x4*)(orow + cb) = *(const f32x4*)(oeb + cb);
      }
    } else {
#pragma unroll
      for (int nf = 0; nf < 4; ++nf) {
        int cb = wn * 64 + nf * 16 + lq * 4;
        f32x4 q4 = *(const f32x4*)(Qrow + cb);
        *(f32x4*)(orow + cb) = acc[mf][nf] + pc[nf] + q4;
      }
    }
  }
}

extern "C" void kernel_launch(void* const* d_in, const int* in_sizes, int n_in,
                              void* d_out, int out_size, void* d_ws, size_t ws_size,
                              hipStream_t stream) {
  const float* node = (const float*)d_in[0];
  const float* edge = (const float*)d_in[1];
  const float* Wn_w = (const float*)d_in[2];
  const float* Wn_b = (const float*)d_in[3];
  const float* Wh_w = (const float*)d_in[4];
  const float* Wh_b = (const float*)d_in[5];
  const float* We_w = (const float*)d_in[6];
  const float* We_b = (const float*)d_in[7];
  const float* Wn2_w = (const float*)d_in[8];
  const float* Wn2_b = (const float*)d_in[9];
  const float* We2_w = (const float*)d_in[10];
  const float* We2_b = (const float*)d_in[11];
  const float* attn_w = (const float*)d_in[12];
  const float* edge_w = (const float*)d_in[13];
  const float* edge_b = (const float*)d_in[14];
  const float* out_n_w = (const float*)d_in[15];
  const float* out_n_b = (const float*)d_in[16];
  const float* out_e_w = (const float*)d_in[17];
  const float* out_e_b = (const float*)d_in[18];

  float* out_node = (float*)d_out;            // 262144
  float* out_edge = ((float*)d_out) + 262144; // 33554432

  float* ws = (float*)d_ws;
  float* node_p = ws;                      // 262144
  float* Whh    = ws + 262144;             // 262144
  float* node_h = ws + 524288;             // 262144
  float* si     = ws + 786432;             // 8192
  float* sjv    = ws + 794624;             // 8192
  float* Pg     = ws + 802816;             // 131072
  float* Qg     = ws + 933888;             // 131072
  float* chg    = ws + 1064960;            // 128
  float* c0g    = ws + 1065088;            // 128
  short* Gt     = (short*)(ws + 1065216);  // 16384 shorts
  short* Vbf    = (short*)(ws + 1073408);  // 2048 shorts
  float* seg    = ws + 1074432;            // 2097152
  short* Tf     = (short*)(ws + 3171584);  // 33554432 shorts = 16777216 floats
  const bool big = ws_size >= (size_t)(3171584 + 16777216) * 4;

  prep_kernel<<<129, 128, 0, stream>>>(We_w, We_b, attn_w, We2_w, We2_b, edge_w, edge_b,
                                       out_e_w, out_e_b, Vbf, chg, c0g, Gt);
  node_in_fused<<<256, 256, 0, stream>>>(node, Wn_w, Wn_b, Wh_w, Wh_b, attn_w, node_p, Whh,
                                         si, sjv);
  if (big) {
    edge_t_kernel<<<1024, 256, 0, stream>>>(edge, Gt, Vbf, chg, Tf, seg);
    attn_fused<<<1024, 256, 0, stream>>>(node_p, Whh, si, sjv, seg, node_h);
    node_out_pq<<<256, 256, 0, stream>>>(node_h, out_n_w, out_n_b, Wn2_w, Wn2_b, edge_w,
                                         out_e_w, out_node, Pg, Qg);
    edge_final_kernel<<<2048, 256, 0, stream>>>(Tf, Pg, Qg, c0g, out_e_b, out_edge);
  } else {
    attn_fallback<<<1024, 256, 0, stream>>>(node_p, Whh, si, sjv, edge, Vbf, chg, node_h);
    node_out_pq<<<256, 256, 0, stream>>>(node_h, out_n_w, out_n_b, Wn2_w, Wn2_b, edge_w,
                                         out_e_w, out_node, Pg, Qg);
    edge_out_fallback<<<2048, 256, 0, stream>>>(edge, Gt, Pg, Qg, c0g, out_e_b, out_edge);
  }
}

// Round 10
// 170.876 us; speedup vs baseline: 1.0847x; 1.0847x over previous
//
#include <hip/hip_runtime.h>

#define Bb 4
#define Ll 256
#define NEG 0.2f

typedef __attribute__((ext_vector_type(8))) short short8;
typedef __attribute__((ext_vector_type(4))) float f32x4;
typedef __attribute__((ext_vector_type(4))) unsigned uint4v;

__device__ __forceinline__ float lrelu(float x) { return x >= 0.f ? x : NEG * x; }

__device__ __forceinline__ short f2bf(float x) {
  unsigned u = __builtin_bit_cast(unsigned, x);
  unsigned r = (u + 0x7FFFu + ((u >> 16) & 1u)) >> 16;
  return (short)r;
}

// pack two f32 -> u32 of 2 bf16 (round half up); elem0 in low 16
__device__ __forceinline__ unsigned pack2bf(float e, float o) {
  unsigned ue = __builtin_bit_cast(unsigned, e);
  unsigned uo = __builtin_bit_cast(unsigned, o);
  return ((ue + 0x8000u) >> 16) | ((uo + 0x8000u) & 0xFFFF0000u);
}

// ---------------- merged prep: blocks 0..127 -> Gsw (bf16 swizzled LDS image of
// Gt[n][k]: byte(n,k) = n*256 + ((2k) ^ ((n&7)<<4)));
// block 128 -> Vbf (bf16 [16][128], rows 8..15 zero), ch(8), c0(128) ----------------
__global__ void prep_kernel(const float* We_w, const float* We_b, const float* attn_w,
                            const float* We2_w, const float* We2_b, const float* edge_w,
                            const float* edge_b, const float* out_e_w, const float* out_e_b,
                            short* Vbf, float* chg, float* c0g, short* Gsw) {
  int blk = blockIdx.x;
  int t = threadIdx.x; // 128 threads
  if (blk < 128) {
    __shared__ float m2[128];
    int c = blk; // k index
    int h = t >> 4, e = t & 15;
    float s = 0.f;
    for (int d = 0; d < 16; ++d) s += We2_w[c * 128 + h * 16 + d] * edge_w[d * 16 + e];
    m2[t] = s;
    __syncthreads();
    float g = 0.f;
    for (int f = 0; f < 128; ++f) g += m2[f] * out_e_w[f * 128 + t];
    int off = t * 256 + ((2 * c) ^ ((t & 7) << 4));
    *(short*)((char*)Gsw + off) = f2bf(g);
  } else {
    __shared__ float b2e[128];
    const float* we = attn_w + 64;
    for (int idx = t; idx < 1024; idx += 128) {
      int c = idx >> 3, h = idx & 7;
      float s = 0.f;
      for (int d = 0; d < 16; ++d) s += We_w[c * 128 + h * 16 + d] * we[d];
      Vbf[h * 128 + c] = f2bf(s);
      Vbf[(h + 8) * 128 + c] = 0;
    }
    if (t < 8) {
      float s = 0.f;
      for (int d = 0; d < 16; ++d) s += We_b[t * 16 + d] * we[d];
      chg[t] = s;
    }
    {
      int h = t >> 4, e = t & 15;
      float s = 0.f;
      for (int d = 0; d < 16; ++d) s += We2_b[h * 16 + d] * edge_w[d * 16 + e];
      b2e[t] = s + edge_b[e];
    }
    __syncthreads();
    float s = out_e_b[t];
    for (int f = 0; f < 128; ++f) s += b2e[f] * out_e_w[f * 128 + t];
    c0g[t] = s;
  }
}

// ---------------- se pass: lean, no LDS, no barrier, high occupancy ----------------
// 2048 blocks = half-slab (128 rows); wave = 32 rows (2 tiles of 16).
// mfma(av=edge rows, vb=V): D[row=lq*4+r][head=lc]
__global__ __launch_bounds__(256) void se_kernel(const float* __restrict__ edge,
                                                 const short* __restrict__ Vbf,
                                                 const float* __restrict__ chg,
                                                 float* __restrict__ seg) {
  int t = threadIdx.x;
  int w = t >> 6, l = t & 63;
  int lc = l & 15, lq = l >> 4;
  int blk = blockIdx.x;
  long rbase = (long)blk * 128;
  short8 vb[4];
#pragma unroll
  for (int ks = 0; ks < 4; ++ks) vb[ks] = *(const short8*)(Vbf + lc * 128 + ks * 32 + lq * 8);
  float chv = (lc < 8) ? chg[lc] : 0.f;
  int slab = blk >> 1;
  int joff = (blk & 1) * 128;

#pragma unroll
  for (int s = 0; s < 2; ++s) {
    int rowb = w * 32 + s * 16;
    f32x4 acc = (f32x4){0.f, 0.f, 0.f, 0.f};
#pragma unroll
    for (int ks = 0; ks < 4; ++ks) {
      const float* ap = edge + (rbase + rowb + lc) * 128 + ks * 32 + lq * 8;
      float4 f0 = *(const float4*)ap;
      float4 f1 = *(const float4*)(ap + 4);
      uint4v u;
      u.x = pack2bf(f0.x, f0.y);
      u.y = pack2bf(f0.z, f0.w);
      u.z = pack2bf(f1.x, f1.y);
      u.w = pack2bf(f1.z, f1.w);
      acc = __builtin_amdgcn_mfma_f32_16x16x32_bf16(__builtin_bit_cast(short8, u), vb[ks], acc,
                                                    0, 0, 0);
    }
    if (lc < 8) {
#pragma unroll
      for (int r = 0; r < 4; ++r) {
        int row = joff + rowb + lq * 4 + r;
        seg[(long)slab * 2048 + row * 8 + lc] = acc[r] + chv;
      }
    }
  }
}

// ---------------- node_in_fused: node_p = node@Wn + b; Whh; si; sj ----------------
__global__ __launch_bounds__(256) void node_in_fused(
    const float* __restrict__ node, const float* __restrict__ Wn_w,
    const float* __restrict__ Wn_b, const float* __restrict__ Wh_w,
    const float* __restrict__ Wh_b, const float* __restrict__ attn_w,
    float* __restrict__ node_p, float* __restrict__ Whh, float* __restrict__ si,
    float* __restrict__ sj) {
  __shared__ float a[4][256];
  __shared__ float np[4][256];
  int t = threadIdx.x;
  int row0 = blockIdx.x * 4;
  for (int q = t; q < 1024; q += 256) a[q >> 8][q & 255] = node[(long)row0 * 256 + q];
  __syncthreads();
  float acc[4];
  float bvv = Wn_b[t];
#pragma unroll
  for (int r = 0; r < 4; ++r) acc[r] = bvv;
  for (int k = 0; k < 256; ++k) {
    float w = Wn_w[k * 256 + t];
#pragma unroll
    for (int r = 0; r < 4; ++r) acc[r] += a[r][k] * w;
  }
#pragma unroll
  for (int r = 0; r < 4; ++r) {
    node_p[(long)(row0 + r) * 256 + t] = acc[r];
    np[r][t] = acc[r];
  }
  __syncthreads();
  int h = t >> 5, e = t & 31;
  float wb2 = Wh_b[e];
#pragma unroll
  for (int r = 0; r < 4; ++r) {
    float s = wb2;
    for (int d = 0; d < 32; ++d) s += np[r][h * 32 + d] * Wh_w[d * 32 + e];
    Whh[(long)(row0 + r) * 256 + t] = s;
  }
  if (t < 64) {
    int r = t >> 4, idx = t & 15, hh = idx & 7;
    const float* w = attn_w + (idx < 8 ? 0 : 32);
    float s = 0.f;
    for (int d = 0; d < 32; ++d) s += np[r][hh * 32 + d] * w[d];
    ((idx < 8) ? si : sj)[(long)(row0 + r) * 8 + hh] = s;
  }
}

// ---------------- attn: softmax + agg from precomputed seg ----------------
__global__ __launch_bounds__(256) void attn_fused(
    const float* __restrict__ node_p, const float* __restrict__ Whh,
    const float* __restrict__ si, const float* __restrict__ sj,
    const float* __restrict__ seg, float* __restrict__ node_h) {
  __shared__ float sjl[2048];
  __shared__ float sel[2048];
  __shared__ float pl[2048];
  __shared__ float sil[8];
  int t = threadIdx.x, bi = blockIdx.x;
  int b = bi >> 8, i = bi & 255;
  for (int q = t; q < 2048; q += 256) sjl[q] = sj[(long)b * 2048 + q];
  for (int q = t; q < 2048; q += 256) sel[q] = seg[(long)bi * 2048 + q];
  if (t < 8) sil[t] = si[(long)bi * 8 + t];
  __syncthreads();

  int g = t >> 5, l32 = t & 31;
  float sc[8];
  float mx = -1e30f;
#pragma unroll
  for (int m = 0; m < 8; ++m) {
    int k = l32 + 32 * m;
    float v = -1e30f;
    if (k < 255) {
      int jj = k + (k >= i ? 1 : 0);
      v = sil[g] + sjl[jj * 8 + g] + sel[jj * 8 + g];
      v = lrelu(v);
    }
    sc[m] = v;
    mx = fmaxf(mx, v);
  }
#pragma unroll
  for (int d = 16; d >= 1; d >>= 1) mx = fmaxf(mx, __shfl_xor(mx, d));
  float sum = 0.f;
#pragma unroll
  for (int m = 0; m < 8; ++m) {
    int k = l32 + 32 * m;
    float e = (k < 255) ? __expf(sc[m] - mx) : 0.f;
    sc[m] = e;
    sum += e;
  }
#pragma unroll
  for (int d = 16; d >= 1; d >>= 1) sum += __shfl_xor(sum, d);
  float inv = 1.f / sum;
#pragma unroll
  for (int m = 0; m < 8; ++m) {
    int k = l32 + 32 * m;
    if (k < 255) pl[k * 8 + g] = sc[m] * inv;
  }
  __syncthreads();

  int h = g;
  const float* wb = Whh + (long)b * 65536 + t;
  float acc0 = 0.f, acc1 = 0.f;
#pragma unroll 8
  for (int j = 0; j < 256; j += 2) {
    int k0 = (j == 0) ? 254 : (j - 1);
    int k1 = j;
    float w0 = (j == i) ? 0.f : pl[k0 * 8 + h];
    float w1 = (j + 1 == i) ? 0.f : pl[k1 * 8 + h];
    acc0 += w0 * wb[(long)j * 256];
    acc1 += w1 * wb[(long)(j + 1) * 256];
  }
  float acc = acc0 + acc1;
  float np = node_p[(long)bi * 256 + t];
  node_h[(long)bi * 256 + t] = np + lrelu(acc);
}

// ---------------- node_out_pq: out_node; node_p2; P/Q ----------------
__global__ __launch_bounds__(256) void node_out_pq(
    const float* __restrict__ node_h, const float* __restrict__ out_n_w,
    const float* __restrict__ out_n_b, const float* __restrict__ Wn2_w,
    const float* __restrict__ Wn2_b, const float* __restrict__ edge_w,
    const float* __restrict__ out_e_w, float* __restrict__ out_node,
    float* __restrict__ Pg, float* __restrict__ Qg) {
  __shared__ float a[4][256];
  __shared__ float b2[4][256];
  __shared__ float ninj[4][256];
  int t = threadIdx.x;
  int row0 = blockIdx.x * 4;
  for (int q = t; q < 1024; q += 256) a[q >> 8][q & 255] = node_h[(long)row0 * 256 + q];
  __syncthreads();
  float acc[4];
  float bv1 = out_n_b[t];
#pragma unroll
  for (int r = 0; r < 4; ++r) acc[r] = bv1;
  for (int k = 0; k < 256; ++k) {
    float w = out_n_w[k * 256 + t];
#pragma unroll
    for (int r = 0; r < 4; ++r) acc[r] += a[r][k] * w;
  }
#pragma unroll
  for (int r = 0; r < 4; ++r) {
    out_node[(long)(row0 + r) * 256 + t] = acc[r];
    b2[r][t] = acc[r];
  }
  __syncthreads();
  float acc2[4];
  float bv2 = Wn2_b[t];
#pragma unroll
  for (int r = 0; r < 4; ++r) acc2[r] = bv2;
  for (int k = 0; k < 256; ++k) {
    float w = Wn2_w[k * 256 + t];
#pragma unroll
    for (int r = 0; r < 4; ++r) acc2[r] += b2[r][k] * w;
  }
#pragma unroll
  for (int r = 0; r < 4; ++r) a[r][t] = acc2[r]; // node_p2
  __syncthreads();
  {
    int f = t & 127, h = f >> 4, e = f & 15;
    const float* w = edge_w + 256 + (t >> 7) * 512; // w_i / w_j
#pragma unroll
    for (int r = 0; r < 4; ++r) {
      float s = 0.f;
      for (int d = 0; d < 32; ++d) s += a[r][h * 32 + d] * w[d * 16 + e];
      ninj[r][t] = s;
    }
  }
  __syncthreads();
  {
    int o = t & 127;
    int half = (t >> 7) * 128;
#pragma unroll
    for (int r = 0; r < 4; ++r) {
      float s = 0.f;
      const float* src = ninj[r] + half;
      for (int f = 0; f < 128; ++f) s += src[f] * out_e_w[f * 128 + o];
      ((t < 128) ? Pg : Qg)[(long)(row0 + r) * 128 + o] = s;
    }
  }
}

// ---------------- edge_out v6: G in LDS (swizzled), mfma(av,bv), coalesced epilogue --
// 1024 blocks = one (b,i) slab; 4 waves x 4 tiles of 16 rows x 128 cols.
// D[row=lq*4+r][col=nf*16+lc]: quarter-wave row-uniform -> Q loads & stores coalesced.
__global__ __launch_bounds__(256) void edge_out_kernel(
    const float* __restrict__ edge, const short* __restrict__ Gsw,
    const float* __restrict__ Pg, const float* __restrict__ Qg,
    const float* __restrict__ c0g, const float* __restrict__ oeb,
    float* __restrict__ out_edge) {
  __shared__ __align__(16) char Gl[32768];
  int t = threadIdx.x;
  int w = t >> 6, l = t & 63;
  int lc = l & 15, lq = l >> 4;
  int bi = blockIdx.x;
  int b = bi >> 8, i = bi & 255;

  {
    const uint4v* gsrc = (const uint4v*)Gsw;
    uint4v* gdst = (uint4v*)Gl;
#pragma unroll
    for (int q = 0; q < 8; ++q) gdst[q * 256 + t] = gsrc[q * 256 + t];
  }
  float pcv[8], oebv[8];
#pragma unroll
  for (int nf = 0; nf < 8; ++nf) {
    int col = nf * 16 + lc;
    pcv[nf] = Pg[(long)bi * 128 + col] + c0g[col];
    oebv[nf] = oeb[col];
  }
  __syncthreads();

  const float* eslab = edge + (long)bi * 32768;
#pragma unroll
  for (int s = 0; s < 4; ++s) {
    int rowb = w * 64 + s * 16;
    f32x4 acc[8];
#pragma unroll
    for (int nf = 0; nf < 8; ++nf) acc[nf] = (f32x4){0.f, 0.f, 0.f, 0.f};
#pragma unroll
    for (int ks = 0; ks < 4; ++ks) {
      const float* ap = eslab + (long)(rowb + lc) * 128 + ks * 32 + lq * 8;
      float4 f0 = *(const float4*)ap;
      float4 f1 = *(const float4*)(ap + 4);
      uint4v u;
      u.x = pack2bf(f0.x, f0.y);
      u.y = pack2bf(f0.z, f0.w);
      u.z = pack2bf(f1.x, f1.y);
      u.w = pack2bf(f1.z, f1.w);
      short8 av = __builtin_bit_cast(short8, u);
#pragma unroll
      for (int nf = 0; nf < 8; ++nf) {
        int col = nf * 16 + lc;
        short8 bvv =
            *(const short8*)(Gl + col * 256 + ((ks * 64 + lq * 16) ^ ((col & 7) << 4)));
        acc[nf] = __builtin_amdgcn_mfma_f32_16x16x32_bf16(av, bvv, acc[nf], 0, 0, 0);
      }
    }
#pragma unroll
    for (int r = 0; r < 4; ++r) {
      int jloc = rowb + lq * 4 + r;
      float* orow = out_edge + ((long)bi * 256 + jloc) * 128;
      const float* Qrow = Qg + (long)(b * 256 + jloc) * 128;
      bool diag = (jloc == i);
#pragma unroll
      for (int nf = 0; nf < 8; ++nf) {
        int col = nf * 16 + lc;
        float v = diag ? oebv[nf] : (acc[nf][r] + pcv[nf] + Qrow[col]);
        orow[col] = v;
      }
    }
  }
}

extern "C" void kernel_launch(void* const* d_in, const int* in_sizes, int n_in,
                              void* d_out, int out_size, void* d_ws, size_t ws_size,
                              hipStream_t stream) {
  const float* node = (const float*)d_in[0];
  const float* edge = (const float*)d_in[1];
  const float* Wn_w = (const float*)d_in[2];
  const float* Wn_b = (const float*)d_in[3];
  const float* Wh_w = (const float*)d_in[4];
  const float* Wh_b = (const float*)d_in[5];
  const float* We_w = (const float*)d_in[6];
  const float* We_b = (const float*)d_in[7];
  const float* Wn2_w = (const float*)d_in[8];
  const float* Wn2_b = (const float*)d_in[9];
  const float* We2_w = (const float*)d_in[10];
  const float* We2_b = (const float*)d_in[11];
  const float* attn_w = (const float*)d_in[12];
  const float* edge_w = (const float*)d_in[13];
  const float* edge_b = (const float*)d_in[14];
  const float* out_n_w = (const float*)d_in[15];
  const float* out_n_b = (const float*)d_in[16];
  const float* out_e_w = (const float*)d_in[17];
  const float* out_e_b = (const float*)d_in[18];

  float* out_node = (float*)d_out;            // 262144
  float* out_edge = ((float*)d_out) + 262144; // 33554432

  float* ws = (float*)d_ws;
  float* node_p = ws;                      // 262144
  float* Whh    = ws + 262144;             // 262144
  float* node_h = ws + 524288;             // 262144
  float* si     = ws + 786432;             // 8192
  float* sjv    = ws + 794624;             // 8192
  float* Pg     = ws + 802816;             // 131072
  float* Qg     = ws + 933888;             // 131072
  float* chg    = ws + 1064960;            // 128
  float* c0g    = ws + 1065088;            // 128
  short* Gsw    = (short*)(ws + 1065216);  // 16384 shorts
  short* Vbf    = (short*)(ws + 1073408);  // 2048 shorts
  float* seg    = ws + 1074432;            // 2097152

  prep_kernel<<<129, 128, 0, stream>>>(We_w, We_b, attn_w, We2_w, We2_b, edge_w, edge_b,
                                       out_e_w, out_e_b, Vbf, chg, c0g, Gsw);
  node_in_fused<<<256, 256, 0, stream>>>(node, Wn_w, Wn_b, Wh_w, Wh_b, attn_w, node_p, Whh,
                                         si, sjv);
  se_kernel<<<2048, 256, 0, stream>>>(edge, Vbf, chg, seg);
  attn_fused<<<1024, 256, 0, stream>>>(node_p, Whh, si, sjv, seg, node_h);
  node_out_pq<<<256, 256, 0, stream>>>(node_h, out_n_w, out_n_b, Wn2_w, Wn2_b, edge_w,
                                       out_e_w, out_node, Pg, Qg);
  edge_out_kernel<<<1024, 256, 0, stream>>>(edge, Gsw, Pg, Qg, c0g, out_e_b, out_edge);
}

// Round 11
// 167.517 us; speedup vs baseline: 1.1064x; 1.0200x over previous
//
#include <hip/hip_runtime.h>

#define Bb 4
#define Ll 256
#define NEG 0.2f

typedef __attribute__((ext_vector_type(8))) short short8;
typedef __attribute__((ext_vector_type(4))) float f32x4;
typedef __attribute__((ext_vector_type(4))) unsigned uint4v;

__device__ __forceinline__ float lrelu(float x) { return x >= 0.f ? x : NEG * x; }

__device__ __forceinline__ short f2bf(float x) {
  unsigned u = __builtin_bit_cast(unsigned, x);
  unsigned r = (u + 0x7FFFu + ((u >> 16) & 1u)) >> 16;
  return (short)r;
}

// pack two f32 -> u32 of 2 bf16 (round half up); elem0 in low 16
__device__ __forceinline__ unsigned pack2bf(float e, float o) {
  unsigned ue = __builtin_bit_cast(unsigned, e);
  unsigned uo = __builtin_bit_cast(unsigned, o);
  return ((ue + 0x8000u) >> 16) | ((uo + 0x8000u) & 0xFFFF0000u);
}

// ---------------- merged prep: blocks 0..127 -> Gsw (bf16 swizzled image of Gt[n][k]);
// block 128 -> Vg (fp32 [128][8], V[c*8+h]), ch(8), c0(128) ----------------
__global__ void prep_kernel(const float* We_w, const float* We_b, const float* attn_w,
                            const float* We2_w, const float* We2_b, const float* edge_w,
                            const float* edge_b, const float* out_e_w, const float* out_e_b,
                            float* Vg, float* chg, float* c0g, short* Gsw) {
  int blk = blockIdx.x;
  int t = threadIdx.x; // 128 threads
  if (blk < 128) {
    __shared__ float m2[128];
    int c = blk; // k index
    int h = t >> 4, e = t & 15;
    float s = 0.f;
    for (int d = 0; d < 16; ++d) s += We2_w[c * 128 + h * 16 + d] * edge_w[d * 16 + e];
    m2[t] = s;
    __syncthreads();
    float g = 0.f;
    for (int f = 0; f < 128; ++f) g += m2[f] * out_e_w[f * 128 + t];
    int off = t * 256 + ((2 * c) ^ ((t & 7) << 4));
    *(short*)((char*)Gsw + off) = f2bf(g);
  } else {
    __shared__ float b2e[128];
    const float* we = attn_w + 64;
    for (int idx = t; idx < 1024; idx += 128) {
      int c = idx >> 3, h = idx & 7;
      float s = 0.f;
      for (int d = 0; d < 16; ++d) s += We_w[c * 128 + h * 16 + d] * we[d];
      Vg[idx] = s; // V[c*8+h]
    }
    if (t < 8) {
      float s = 0.f;
      for (int d = 0; d < 16; ++d) s += We_b[t * 16 + d] * we[d];
      chg[t] = s;
    }
    {
      int h = t >> 4, e = t & 15;
      float s = 0.f;
      for (int d = 0; d < 16; ++d) s += We2_b[h * 16 + d] * edge_w[d * 16 + e];
      b2e[t] = s + edge_b[e];
    }
    __syncthreads();
    float s = out_e_b[t];
    for (int f = 0; f < 128; ++f) s += b2e[f] * out_e_w[f * 128 + t];
    c0g[t] = s;
  }
}

// ---------------- se v2 (r0-proven): contiguous float4 reads + butterfly reduce ------
// 16 lanes per edge row; wave reads 2KB contiguous; grid-stride.
__global__ __launch_bounds__(256) void se_kernel(const float* __restrict__ edge,
                                                 const float* __restrict__ Vg,
                                                 const float* __restrict__ chg,
                                                 float* __restrict__ se) {
  int t = threadIdx.x;
  int l16 = t & 15;
  long gid = ((long)blockIdx.x * 256 + t) >> 4;
  long ngroups = ((long)gridDim.x * 256) >> 4;
  float vreg[8][8];
#pragma unroll
  for (int ci = 0; ci < 8; ++ci) {
    int c = (ci < 4) ? (l16 * 4 + ci) : (64 + l16 * 4 + (ci - 4));
#pragma unroll
    for (int h = 0; h < 8; ++h) vreg[ci][h] = Vg[c * 8 + h];
  }
  float chv = chg[(l16 >> 1) & 7];
  const long NR = (long)Bb * Ll * Ll;
  for (long row = gid; row < NR; row += ngroups) {
    const float4* er = reinterpret_cast<const float4*>(edge + row * 128);
    float4 e0 = er[l16];
    float4 e1 = er[16 + l16];
    float p[8];
#pragma unroll
    for (int h = 0; h < 8; ++h)
      p[h] = e0.x * vreg[0][h] + e0.y * vreg[1][h] + e0.z * vreg[2][h] + e0.w * vreg[3][h] +
             e1.x * vreg[4][h] + e1.y * vreg[5][h] + e1.z * vreg[6][h] + e1.w * vreg[7][h];
    bool hi8 = (l16 & 8) != 0;
    float q[4];
#pragma unroll
    for (int h = 0; h < 4; ++h) {
      float keep = hi8 ? p[h + 4] : p[h];
      float send = hi8 ? p[h] : p[h + 4];
      q[h] = keep + __shfl_xor(send, 8);
    }
    bool hi4 = (l16 & 4) != 0;
    float r2[2];
#pragma unroll
    for (int h = 0; h < 2; ++h) {
      float keep = hi4 ? q[h + 2] : q[h];
      float send = hi4 ? q[h] : q[h + 2];
      r2[h] = keep + __shfl_xor(send, 4);
    }
    bool hi2 = (l16 & 2) != 0;
    float s = (hi2 ? r2[1] : r2[0]) + __shfl_xor(hi2 ? r2[0] : r2[1], 2);
    s += __shfl_xor(s, 1);
    s += chv;
    if ((l16 & 1) == 0) se[row * 8 + ((l16 >> 1) & 7)] = s;
  }
}

// ---------------- node_in_fused: node_p = node@Wn + b; Whh; si; sj ----------------
__global__ __launch_bounds__(256) void node_in_fused(
    const float* __restrict__ node, const float* __restrict__ Wn_w,
    const float* __restrict__ Wn_b, const float* __restrict__ Wh_w,
    const float* __restrict__ Wh_b, const float* __restrict__ attn_w,
    float* __restrict__ node_p, float* __restrict__ Whh, float* __restrict__ si,
    float* __restrict__ sj) {
  __shared__ float a[4][256];
  __shared__ float np[4][256];
  int t = threadIdx.x;
  int row0 = blockIdx.x * 4;
  for (int q = t; q < 1024; q += 256) a[q >> 8][q & 255] = node[(long)row0 * 256 + q];
  __syncthreads();
  float acc[4];
  float bvv = Wn_b[t];
#pragma unroll
  for (int r = 0; r < 4; ++r) acc[r] = bvv;
  for (int k = 0; k < 256; ++k) {
    float w = Wn_w[k * 256 + t];
#pragma unroll
    for (int r = 0; r < 4; ++r) acc[r] += a[r][k] * w;
  }
#pragma unroll
  for (int r = 0; r < 4; ++r) {
    node_p[(long)(row0 + r) * 256 + t] = acc[r];
    np[r][t] = acc[r];
  }
  __syncthreads();
  int h = t >> 5, e = t & 31;
  float wb2 = Wh_b[e];
#pragma unroll
  for (int r = 0; r < 4; ++r) {
    float s = wb2;
    for (int d = 0; d < 32; ++d) s += np[r][h * 32 + d] * Wh_w[d * 32 + e];
    Whh[(long)(row0 + r) * 256 + t] = s;
  }
  if (t < 64) {
    int r = t >> 4, idx = t & 15, hh = idx & 7;
    const float* w = attn_w + (idx < 8 ? 0 : 32);
    float s = 0.f;
    for (int d = 0; d < 32; ++d) s += np[r][hh * 32 + d] * w[d];
    ((idx < 8) ? si : sj)[(long)(row0 + r) * 8 + hh] = s;
  }
}

// ---------------- attn: softmax + agg from precomputed seg ----------------
__global__ __launch_bounds__(256) void attn_fused(
    const float* __restrict__ node_p, const float* __restrict__ Whh,
    const float* __restrict__ si, const float* __restrict__ sj,
    const float* __restrict__ seg, float* __restrict__ node_h) {
  __shared__ float sjl[2048];
  __shared__ float sel[2048];
  __shared__ float pl[2048];
  __shared__ float sil[8];
  int t = threadIdx.x, bi = blockIdx.x;
  int b = bi >> 8, i = bi & 255;
  for (int q = t; q < 2048; q += 256) sjl[q] = sj[(long)b * 2048 + q];
  for (int q = t; q < 2048; q += 256) sel[q] = seg[(long)bi * 2048 + q];
  if (t < 8) sil[t] = si[(long)bi * 8 + t];
  __syncthreads();

  int g = t >> 5, l32 = t & 31;
  float sc[8];
  float mx = -1e30f;
#pragma unroll
  for (int m = 0; m < 8; ++m) {
    int k = l32 + 32 * m;
    float v = -1e30f;
    if (k < 255) {
      int jj = k + (k >= i ? 1 : 0);
      v = sil[g] + sjl[jj * 8 + g] + sel[jj * 8 + g];
      v = lrelu(v);
    }
    sc[m] = v;
    mx = fmaxf(mx, v);
  }
#pragma unroll
  for (int d = 16; d >= 1; d >>= 1) mx = fmaxf(mx, __shfl_xor(mx, d));
  float sum = 0.f;
#pragma unroll
  for (int m = 0; m < 8; ++m) {
    int k = l32 + 32 * m;
    float e = (k < 255) ? __expf(sc[m] - mx) : 0.f;
    sc[m] = e;
    sum += e;
  }
#pragma unroll
  for (int d = 16; d >= 1; d >>= 1) sum += __shfl_xor(sum, d);
  float inv = 1.f / sum;
#pragma unroll
  for (int m = 0; m < 8; ++m) {
    int k = l32 + 32 * m;
    if (k < 255) pl[k * 8 + g] = sc[m] * inv;
  }
  __syncthreads();

  int h = g;
  const float* wb = Whh + (long)b * 65536 + t;
  float acc0 = 0.f, acc1 = 0.f;
#pragma unroll 8
  for (int j = 0; j < 256; j += 2) {
    int k0 = (j == 0) ? 254 : (j - 1);
    int k1 = j;
    float w0 = (j == i) ? 0.f : pl[k0 * 8 + h];
    float w1 = (j + 1 == i) ? 0.f : pl[k1 * 8 + h];
    acc0 += w0 * wb[(long)j * 256];
    acc1 += w1 * wb[(long)(j + 1) * 256];
  }
  float acc = acc0 + acc1;
  float np = node_p[(long)bi * 256 + t];
  node_h[(long)bi * 256 + t] = np + lrelu(acc);
}

// ---------------- node_out_pq: out_node; node_p2; P/Q ----------------
__global__ __launch_bounds__(256) void node_out_pq(
    const float* __restrict__ node_h, const float* __restrict__ out_n_w,
    const float* __restrict__ out_n_b, const float* __restrict__ Wn2_w,
    const float* __restrict__ Wn2_b, const float* __restrict__ edge_w,
    const float* __restrict__ out_e_w, float* __restrict__ out_node,
    float* __restrict__ Pg, float* __restrict__ Qg) {
  __shared__ float a[4][256];
  __shared__ float b2[4][256];
  __shared__ float ninj[4][256];
  int t = threadIdx.x;
  int row0 = blockIdx.x * 4;
  for (int q = t; q < 1024; q += 256) a[q >> 8][q & 255] = node_h[(long)row0 * 256 + q];
  __syncthreads();
  float acc[4];
  float bv1 = out_n_b[t];
#pragma unroll
  for (int r = 0; r < 4; ++r) acc[r] = bv1;
  for (int k = 0; k < 256; ++k) {
    float w = out_n_w[k * 256 + t];
#pragma unroll
    for (int r = 0; r < 4; ++r) acc[r] += a[r][k] * w;
  }
#pragma unroll
  for (int r = 0; r < 4; ++r) {
    out_node[(long)(row0 + r) * 256 + t] = acc[r];
    b2[r][t] = acc[r];
  }
  __syncthreads();
  float acc2[4];
  float bv2 = Wn2_b[t];
#pragma unroll
  for (int r = 0; r < 4; ++r) acc2[r] = bv2;
  for (int k = 0; k < 256; ++k) {
    float w = Wn2_w[k * 256 + t];
#pragma unroll
    for (int r = 0; r < 4; ++r) acc2[r] += b2[r][k] * w;
  }
#pragma unroll
  for (int r = 0; r < 4; ++r) a[r][t] = acc2[r]; // node_p2
  __syncthreads();
  {
    int f = t & 127, h = f >> 4, e = f & 15;
    const float* w = edge_w + 256 + (t >> 7) * 512; // w_i / w_j
#pragma unroll
    for (int r = 0; r < 4; ++r) {
      float s = 0.f;
      for (int d = 0; d < 32; ++d) s += a[r][h * 32 + d] * w[d * 16 + e];
      ninj[r][t] = s;
    }
  }
  __syncthreads();
  {
    int o = t & 127;
    int half = (t >> 7) * 128;
#pragma unroll
    for (int r = 0; r < 4; ++r) {
      float s = 0.f;
      const float* src = ninj[r] + half;
      for (int f = 0; f < 128; ++f) s += src[f] * out_e_w[f * 128 + o];
      ((t < 128) ? Pg : Qg)[(long)(row0 + r) * 128 + o] = s;
    }
  }
}

// ---------------- edge_out v7: 2048 blocks x 128 rows; G in LDS (swizzled);
// mfma(av,bv); quarter-wave row-uniform coalesced epilogue ----------------
__global__ __launch_bounds__(256) void edge_out_kernel(
    const float* __restrict__ edge, const short* __restrict__ Gsw,
    const float* __restrict__ Pg, const float* __restrict__ Qg,
    const float* __restrict__ c0g, const float* __restrict__ oeb,
    float* __restrict__ out_edge) {
  __shared__ __align__(16) char Gl[32768];
  int t = threadIdx.x;
  int w = t >> 6, l = t & 63;
  int lc = l & 15, lq = l >> 4;
  int blk = blockIdx.x;
  int bi = blk >> 1;          // (b,i) slab
  int jh = (blk & 1) * 128;   // which half of j range
  int b = bi >> 8, i = bi & 255;

  {
    const uint4v* gsrc = (const uint4v*)Gsw;
    uint4v* gdst = (uint4v*)Gl;
#pragma unroll
    for (int q = 0; q < 8; ++q) gdst[q * 256 + t] = gsrc[q * 256 + t];
  }
  float pcv[8], oebv[8];
#pragma unroll
  for (int nf = 0; nf < 8; ++nf) {
    int col = nf * 16 + lc;
    pcv[nf] = Pg[(long)bi * 128 + col] + c0g[col];
    oebv[nf] = oeb[col];
  }
  __syncthreads();

  const float* eslab = edge + (long)bi * 32768;
#pragma unroll
  for (int s = 0; s < 2; ++s) {
    int rowb = jh + w * 32 + s * 16;
    f32x4 acc[8];
#pragma unroll
    for (int nf = 0; nf < 8; ++nf) acc[nf] = (f32x4){0.f, 0.f, 0.f, 0.f};
#pragma unroll
    for (int ks = 0; ks < 4; ++ks) {
      const float* ap = eslab + (long)(rowb + lc) * 128 + ks * 32 + lq * 8;
      float4 f0 = *(const float4*)ap;
      float4 f1 = *(const float4*)(ap + 4);
      uint4v u;
      u.x = pack2bf(f0.x, f0.y);
      u.y = pack2bf(f0.z, f0.w);
      u.z = pack2bf(f1.x, f1.y);
      u.w = pack2bf(f1.z, f1.w);
      short8 av = __builtin_bit_cast(short8, u);
#pragma unroll
      for (int nf = 0; nf < 8; ++nf) {
        int col = nf * 16 + lc;
        short8 bvv =
            *(const short8*)(Gl + col * 256 + ((ks * 64 + lq * 16) ^ ((col & 7) << 4)));
        acc[nf] = __builtin_amdgcn_mfma_f32_16x16x32_bf16(av, bvv, acc[nf], 0, 0, 0);
      }
    }
#pragma unroll
    for (int r = 0; r < 4; ++r) {
      int jloc = rowb + lq * 4 + r;
      float* orow = out_edge + ((long)bi * 256 + jloc) * 128;
      const float* Qrow = Qg + (long)(b * 256 + jloc) * 128;
      bool diag = (jloc == i);
#pragma unroll
      for (int nf = 0; nf < 8; ++nf) {
        int col = nf * 16 + lc;
        float v = diag ? oebv[nf] : (acc[nf][r] + pcv[nf] + Qrow[col]);
        orow[col] = v;
      }
    }
  }
}

extern "C" void kernel_launch(void* const* d_in, const int* in_sizes, int n_in,
                              void* d_out, int out_size, void* d_ws, size_t ws_size,
                              hipStream_t stream) {
  const float* node = (const float*)d_in[0];
  const float* edge = (const float*)d_in[1];
  const float* Wn_w = (const float*)d_in[2];
  const float* Wn_b = (const float*)d_in[3];
  const float* Wh_w = (const float*)d_in[4];
  const float* Wh_b = (const float*)d_in[5];
  const float* We_w = (const float*)d_in[6];
  const float* We_b = (const float*)d_in[7];
  const float* Wn2_w = (const float*)d_in[8];
  const float* Wn2_b = (const float*)d_in[9];
  const float* We2_w = (const float*)d_in[10];
  const float* We2_b = (const float*)d_in[11];
  const float* attn_w = (const float*)d_in[12];
  const float* edge_w = (const float*)d_in[13];
  const float* edge_b = (const float*)d_in[14];
  const float* out_n_w = (const float*)d_in[15];
  const float* out_n_b = (const float*)d_in[16];
  const float* out_e_w = (const float*)d_in[17];
  const float* out_e_b = (const float*)d_in[18];

  float* out_node = (float*)d_out;            // 262144
  float* out_edge = ((float*)d_out) + 262144; // 33554432

  float* ws = (float*)d_ws;
  float* node_p = ws;                      // 262144
  float* Whh    = ws + 262144;             // 262144
  float* node_h = ws + 524288;             // 262144
  float* si     = ws + 786432;             // 8192
  float* sjv    = ws + 794624;             // 8192
  float* Pg     = ws + 802816;             // 131072
  float* Qg     = ws + 933888;             // 131072
  float* chg    = ws + 1064960;            // 128
  float* c0g    = ws + 1065088;            // 128
  short* Gsw    = (short*)(ws + 1065216);  // 16384 shorts
  float* Vg     = ws + 1073408;            // 1024
  float* seg    = ws + 1074432;            // 2097152

  prep_kernel<<<129, 128, 0, stream>>>(We_w, We_b, attn_w, We2_w, We2_b, edge_w, edge_b,
                                       out_e_w, out_e_b, Vg, chg, c0g, Gsw);
  node_in_fused<<<256, 256, 0, stream>>>(node, Wn_w, Wn_b, Wh_w, Wh_b, attn_w, node_p, Whh,
                                         si, sjv);
  se_kernel<<<2048, 256, 0, stream>>>(edge, Vg, chg, seg);
  attn_fused<<<1024, 256, 0, stream>>>(node_p, Whh, si, sjv, seg, node_h);
  node_out_pq<<<256, 256, 0, stream>>>(node_h, out_n_w, out_n_b, Wn2_w, Wn2_b, edge_w,
                                       out_e_w, out_node, Pg, Qg);
  edge_out_kernel<<<2048, 256, 0, stream>>>(edge, Gsw, Pg, Qg, c0g, out_e_b, out_edge);
}

// Round 12
// 164.152 us; speedup vs baseline: 1.1291x; 1.0205x over previous
//
#include <hip/hip_runtime.h>

#define Bb 4
#define Ll 256
#define NEG 0.2f

typedef __attribute__((ext_vector_type(8))) short short8;
typedef __attribute__((ext_vector_type(4))) float f32x4;
typedef __attribute__((ext_vector_type(4))) unsigned uint4v;

__device__ __forceinline__ float lrelu(float x) { return x >= 0.f ? x : NEG * x; }

__device__ __forceinline__ short f2bf(float x) {
  unsigned u = __builtin_bit_cast(unsigned, x);
  unsigned r = (u + 0x7FFFu + ((u >> 16) & 1u)) >> 16;
  return (short)r;
}

// pack two f32 -> u32 of 2 bf16 (round half up); elem0 in low 16
__device__ __forceinline__ unsigned pack2bf(float e, float o) {
  unsigned ue = __builtin_bit_cast(unsigned, e);
  unsigned uo = __builtin_bit_cast(unsigned, o);
  return ((ue + 0x8000u) >> 16) | ((uo + 0x8000u) & 0xFFFF0000u);
}

// ---------------- merged prep: blocks 0..127 -> Gt (LINEAR bf16 [n][k]);
// block 128 -> Vg (fp32 [128][8], V[c*8+h]), ch(8), c0(128) ----------------
__global__ void prep_kernel(const float* We_w, const float* We_b, const float* attn_w,
                            const float* We2_w, const float* We2_b, const float* edge_w,
                            const float* edge_b, const float* out_e_w, const float* out_e_b,
                            float* Vg, float* chg, float* c0g, short* Gt) {
  int blk = blockIdx.x;
  int t = threadIdx.x; // 128 threads
  if (blk < 128) {
    __shared__ float m2[128];
    int c = blk; // k index
    int h = t >> 4, e = t & 15;
    float s = 0.f;
    for (int d = 0; d < 16; ++d) s += We2_w[c * 128 + h * 16 + d] * edge_w[d * 16 + e];
    m2[t] = s;
    __syncthreads();
    float g = 0.f;
    for (int f = 0; f < 128; ++f) g += m2[f] * out_e_w[f * 128 + t];
    Gt[t * 128 + c] = f2bf(g);
  } else {
    __shared__ float b2e[128];
    const float* we = attn_w + 64;
    for (int idx = t; idx < 1024; idx += 128) {
      int c = idx >> 3, h = idx & 7;
      float s = 0.f;
      for (int d = 0; d < 16; ++d) s += We_w[c * 128 + h * 16 + d] * we[d];
      Vg[idx] = s; // V[c*8+h]
    }
    if (t < 8) {
      float s = 0.f;
      for (int d = 0; d < 16; ++d) s += We_b[t * 16 + d] * we[d];
      chg[t] = s;
    }
    {
      int h = t >> 4, e = t & 15;
      float s = 0.f;
      for (int d = 0; d < 16; ++d) s += We2_b[h * 16 + d] * edge_w[d * 16 + e];
      b2e[t] = s + edge_b[e];
    }
    __syncthreads();
    float s = out_e_b[t];
    for (int f = 0; f < 128; ++f) s += b2e[f] * out_e_w[f * 128 + t];
    c0g[t] = s;
  }
}

// ---------------- se v2 (r0-proven): contiguous float4 reads + butterfly reduce ------
__global__ __launch_bounds__(256) void se_kernel(const float* __restrict__ edge,
                                                 const float* __restrict__ Vg,
                                                 const float* __restrict__ chg,
                                                 float* __restrict__ se) {
  int t = threadIdx.x;
  int l16 = t & 15;
  long gid = ((long)blockIdx.x * 256 + t) >> 4;
  long ngroups = ((long)gridDim.x * 256) >> 4;
  float vreg[8][8];
#pragma unroll
  for (int ci = 0; ci < 8; ++ci) {
    int c = (ci < 4) ? (l16 * 4 + ci) : (64 + l16 * 4 + (ci - 4));
#pragma unroll
    for (int h = 0; h < 8; ++h) vreg[ci][h] = Vg[c * 8 + h];
  }
  float chv = chg[(l16 >> 1) & 7];
  const long NR = (long)Bb * Ll * Ll;
  for (long row = gid; row < NR; row += ngroups) {
    const float4* er = reinterpret_cast<const float4*>(edge + row * 128);
    float4 e0 = er[l16];
    float4 e1 = er[16 + l16];
    float p[8];
#pragma unroll
    for (int h = 0; h < 8; ++h)
      p[h] = e0.x * vreg[0][h] + e0.y * vreg[1][h] + e0.z * vreg[2][h] + e0.w * vreg[3][h] +
             e1.x * vreg[4][h] + e1.y * vreg[5][h] + e1.z * vreg[6][h] + e1.w * vreg[7][h];
    bool hi8 = (l16 & 8) != 0;
    float q[4];
#pragma unroll
    for (int h = 0; h < 4; ++h) {
      float keep = hi8 ? p[h + 4] : p[h];
      float send = hi8 ? p[h] : p[h + 4];
      q[h] = keep + __shfl_xor(send, 8);
    }
    bool hi4 = (l16 & 4) != 0;
    float r2[2];
#pragma unroll
    for (int h = 0; h < 2; ++h) {
      float keep = hi4 ? q[h + 2] : q[h];
      float send = hi4 ? q[h] : q[h + 2];
      r2[h] = keep + __shfl_xor(send, 4);
    }
    bool hi2 = (l16 & 2) != 0;
    float s = (hi2 ? r2[1] : r2[0]) + __shfl_xor(hi2 ? r2[0] : r2[1], 2);
    s += __shfl_xor(s, 1);
    s += chv;
    if ((l16 & 1) == 0) se[row * 8 + ((l16 >> 1) & 7)] = s;
  }
}

// ---------------- node_in_fused: node_p = node@Wn + b; Whh; si; sj ----------------
__global__ __launch_bounds__(256) void node_in_fused(
    const float* __restrict__ node, const float* __restrict__ Wn_w,
    const float* __restrict__ Wn_b, const float* __restrict__ Wh_w,
    const float* __restrict__ Wh_b, const float* __restrict__ attn_w,
    float* __restrict__ node_p, float* __restrict__ Whh, float* __restrict__ si,
    float* __restrict__ sj) {
  __shared__ float a[4][256];
  __shared__ float np[4][256];
  int t = threadIdx.x;
  int row0 = blockIdx.x * 4;
  for (int q = t; q < 1024; q += 256) a[q >> 8][q & 255] = node[(long)row0 * 256 + q];
  __syncthreads();
  float acc[4];
  float bvv = Wn_b[t];
#pragma unroll
  for (int r = 0; r < 4; ++r) acc[r] = bvv;
  for (int k = 0; k < 256; ++k) {
    float w = Wn_w[k * 256 + t];
#pragma unroll
    for (int r = 0; r < 4; ++r) acc[r] += a[r][k] * w;
  }
#pragma unroll
  for (int r = 0; r < 4; ++r) {
    node_p[(long)(row0 + r) * 256 + t] = acc[r];
    np[r][t] = acc[r];
  }
  __syncthreads();
  int h = t >> 5, e = t & 31;
  float wb2 = Wh_b[e];
#pragma unroll
  for (int r = 0; r < 4; ++r) {
    float s = wb2;
    for (int d = 0; d < 32; ++d) s += np[r][h * 32 + d] * Wh_w[d * 32 + e];
    Whh[(long)(row0 + r) * 256 + t] = s;
  }
  if (t < 64) {
    int r = t >> 4, idx = t & 15, hh = idx & 7;
    const float* w = attn_w + (idx < 8 ? 0 : 32);
    float s = 0.f;
    for (int d = 0; d < 32; ++d) s += np[r][hh * 32 + d] * w[d];
    ((idx < 8) ? si : sj)[(long)(row0 + r) * 8 + hh] = s;
  }
}

// ---------------- attn: softmax + agg from precomputed seg ----------------
__global__ __launch_bounds__(256) void attn_fused(
    const float* __restrict__ node_p, const float* __restrict__ Whh,
    const float* __restrict__ si, const float* __restrict__ sj,
    const float* __restrict__ seg, float* __restrict__ node_h) {
  __shared__ float sjl[2048];
  __shared__ float sel[2048];
  __shared__ float pl[2048];
  __shared__ float sil[8];
  int t = threadIdx.x, bi = blockIdx.x;
  int b = bi >> 8, i = bi & 255;
  for (int q = t; q < 2048; q += 256) sjl[q] = sj[(long)b * 2048 + q];
  for (int q = t; q < 2048; q += 256) sel[q] = seg[(long)bi * 2048 + q];
  if (t < 8) sil[t] = si[(long)bi * 8 + t];
  __syncthreads();

  int g = t >> 5, l32 = t & 31;
  float sc[8];
  float mx = -1e30f;
#pragma unroll
  for (int m = 0; m < 8; ++m) {
    int k = l32 + 32 * m;
    float v = -1e30f;
    if (k < 255) {
      int jj = k + (k >= i ? 1 : 0);
      v = sil[g] + sjl[jj * 8 + g] + sel[jj * 8 + g];
      v = lrelu(v);
    }
    sc[m] = v;
    mx = fmaxf(mx, v);
  }
#pragma unroll
  for (int d = 16; d >= 1; d >>= 1) mx = fmaxf(mx, __shfl_xor(mx, d));
  float sum = 0.f;
#pragma unroll
  for (int m = 0; m < 8; ++m) {
    int k = l32 + 32 * m;
    float e = (k < 255) ? __expf(sc[m] - mx) : 0.f;
    sc[m] = e;
    sum += e;
  }
#pragma unroll
  for (int d = 16; d >= 1; d >>= 1) sum += __shfl_xor(sum, d);
  float inv = 1.f / sum;
#pragma unroll
  for (int m = 0; m < 8; ++m) {
    int k = l32 + 32 * m;
    if (k < 255) pl[k * 8 + g] = sc[m] * inv;
  }
  __syncthreads();

  int h = g;
  const float* wb = Whh + (long)b * 65536 + t;
  float acc0 = 0.f, acc1 = 0.f;
#pragma unroll 8
  for (int j = 0; j < 256; j += 2) {
    int k0 = (j == 0) ? 254 : (j - 1);
    int k1 = j;
    float w0 = (j == i) ? 0.f : pl[k0 * 8 + h];
    float w1 = (j + 1 == i) ? 0.f : pl[k1 * 8 + h];
    acc0 += w0 * wb[(long)j * 256];
    acc1 += w1 * wb[(long)(j + 1) * 256];
  }
  float acc = acc0 + acc1;
  float np = node_p[(long)bi * 256 + t];
  node_h[(long)bi * 256 + t] = np + lrelu(acc);
}

// ---------------- node_out_pq: out_node; node_p2; P/Q ----------------
__global__ __launch_bounds__(256) void node_out_pq(
    const float* __restrict__ node_h, const float* __restrict__ out_n_w,
    const float* __restrict__ out_n_b, const float* __restrict__ Wn2_w,
    const float* __restrict__ Wn2_b, const float* __restrict__ edge_w,
    const float* __restrict__ out_e_w, float* __restrict__ out_node,
    float* __restrict__ Pg, float* __restrict__ Qg) {
  __shared__ float a[4][256];
  __shared__ float b2[4][256];
  __shared__ float ninj[4][256];
  int t = threadIdx.x;
  int row0 = blockIdx.x * 4;
  for (int q = t; q < 1024; q += 256) a[q >> 8][q & 255] = node_h[(long)row0 * 256 + q];
  __syncthreads();
  float acc[4];
  float bv1 = out_n_b[t];
#pragma unroll
  for (int r = 0; r < 4; ++r) acc[r] = bv1;
  for (int k = 0; k < 256; ++k) {
    float w = out_n_w[k * 256 + t];
#pragma unroll
    for (int r = 0; r < 4; ++r) acc[r] += a[r][k] * w;
  }
#pragma unroll
  for (int r = 0; r < 4; ++r) {
    out_node[(long)(row0 + r) * 256 + t] = acc[r];
    b2[r][t] = acc[r];
  }
  __syncthreads();
  float acc2[4];
  float bv2 = Wn2_b[t];
#pragma unroll
  for (int r = 0; r < 4; ++r) acc2[r] = bv2;
  for (int k = 0; k < 256; ++k) {
    float w = Wn2_w[k * 256 + t];
#pragma unroll
    for (int r = 0; r < 4; ++r) acc2[r] += b2[r][k] * w;
  }
#pragma unroll
  for (int r = 0; r < 4; ++r) a[r][t] = acc2[r]; // node_p2
  __syncthreads();
  {
    int f = t & 127, h = f >> 4, e = f & 15;
    const float* w = edge_w + 256 + (t >> 7) * 512; // w_i / w_j
#pragma unroll
    for (int r = 0; r < 4; ++r) {
      float s = 0.f;
      for (int d = 0; d < 32; ++d) s += a[r][h * 32 + d] * w[d * 16 + e];
      ninj[r][t] = s;
    }
  }
  __syncthreads();
  {
    int o = t & 127;
    int half = (t >> 7) * 128;
#pragma unroll
    for (int r = 0; r < 4; ++r) {
      float s = 0.f;
      const float* src = ninj[r] + half;
      for (int f = 0; f < 128; ++f) s += src[f] * out_e_w[f * 128 + o];
      ((t < 128) ? Pg : Qg)[(long)(row0 + r) * 128 + o] = s;
    }
  }
}

// ---------------- edge_out v8: persistent blocks, gload_lds staging, counted-vmcnt
// pipeline (raw s_barrier, no mid-loop drain). 1024 blocks x 8 tiles of 32x128.
// Wave = 16 rows x 64 cols. D[row=lq*4+r][col=nf*16+lc] (v7-verified mapping).
#define TPB_E 8
__global__ __launch_bounds__(256, 3) void edge_out_kernel(
    const float* __restrict__ edge, const short* __restrict__ Gt,
    const float* __restrict__ Pg, const float* __restrict__ Qg,
    const float* __restrict__ c0g, const float* __restrict__ oeb,
    float* __restrict__ out_edge) {
  __shared__ __align__(16) float abuf[2][32 * 128]; // 2 x 16 KB, row-swizzled image
  int t = threadIdx.x;
  int l = t & 63, wid = t >> 6;
  int wm = wid >> 1, wn = wid & 1;
  int lc = l & 15, lq = l >> 4;

  // G fragments in registers (linear Gt, r8-verified load pattern)
  short8 bv[4][4];
#pragma unroll
  for (int ks = 0; ks < 4; ++ks)
#pragma unroll
    for (int nf = 0; nf < 4; ++nf)
      bv[ks][nf] = *(const short8*)(Gt + (wn * 64 + nf * 16 + lc) * 128 + ks * 32 + lq * 8);

  float oebv[4];
#pragma unroll
  for (int nf = 0; nf < 4; ++nf) oebv[nf] = oeb[wn * 64 + nf * 16 + lc];

  long tile0 = (long)blockIdx.x * TPB_E;

  // r9-verified staging: pre-swizzled global source, linear LDS dest
  auto stage = [&](int buf, long tile) {
#pragma unroll
    for (int q = 0; q < 4; ++q) {
      int L = q * 256 + t; // 16B chunk index
      int row = L >> 5, c4 = L & 31;
      int scol = (c4 * 4) ^ ((row & 7) << 2); // float index within row
      const float* gp = edge + (tile * 32 + row) * 128 + scol;
      char* lp = (char*)abuf[buf] + q * 4096 + wid * 1024;
      __builtin_amdgcn_global_load_lds(
          (const __attribute__((address_space(1))) unsigned*)gp,
          (__attribute__((address_space(3))) unsigned*)lp, 16, 0, 0);
    }
  };

  stage(0, tile0);
  __syncthreads(); // prologue: full drain once

  int cur = 0;
  for (int tt = 0; tt < TPB_E; ++tt) {
    long tile = tile0 + tt;
    // prefetch next tile; stays in flight through this tile's compute
    if (tt + 1 < TPB_E) stage(cur ^ 1, tile + 1);

    int bi = (int)(tile >> 3);
    int b = bi >> 8, i = bi & 255;
    int row0loc = (int)(tile & 7) * 32;

    float pcv[4];
#pragma unroll
    for (int nf = 0; nf < 4; ++nf) {
      int col = wn * 64 + nf * 16 + lc;
      pcv[nf] = Pg[(long)bi * 128 + col] + c0g[col];
    }

    const char* rbase = (const char*)abuf[cur] + (wm * 16 + lc) * 512;
    int sw = ((wm * 16 + lc) & 7) << 4;

    f32x4 acc[4];
#pragma unroll
    for (int nf = 0; nf < 4; ++nf) acc[nf] = (f32x4){0.f, 0.f, 0.f, 0.f};
#pragma unroll
    for (int ks = 0; ks < 4; ++ks) {
      int cb = ks * 128 + lq * 32;
      float4 f0 = *(const float4*)(rbase + (cb ^ sw));
      float4 f1 = *(const float4*)(rbase + ((cb + 16) ^ sw));
      uint4v u;
      u.x = pack2bf(f0.x, f0.y);
      u.y = pack2bf(f0.z, f0.w);
      u.z = pack2bf(f1.x, f1.y);
      u.w = pack2bf(f1.z, f1.w);
      short8 av = __builtin_bit_cast(short8, u);
#pragma unroll
      for (int nf = 0; nf < 4; ++nf)
        acc[nf] = __builtin_amdgcn_mfma_f32_16x16x32_bf16(av, bv[ks][nf], acc[nf], 0, 0, 0);
    }

#pragma unroll
    for (int r = 0; r < 4; ++r) {
      int jloc = row0loc + wm * 16 + lq * 4 + r;
      float* orow = out_edge + ((long)bi * 256 + jloc) * 128;
      const float* Qrow = Qg + (long)(b * 256 + jloc) * 128;
      bool diag = (jloc == i);
#pragma unroll
      for (int nf = 0; nf < 4; ++nf) {
        int col = wn * 64 + nf * 16 + lc;
        float v = diag ? oebv[nf] : (acc[nf][r] + pcv[nf] + Qrow[col]);
        orow[col] = v;
      }
    }

    // counted wait: stage loads (oldest) certified done; stores (<=16 newest) keep flying
    asm volatile("s_waitcnt vmcnt(16)" ::: "memory");
    __builtin_amdgcn_s_barrier();
    asm volatile("" ::: "memory");
    cur ^= 1;
  }
}

extern "C" void kernel_launch(void* const* d_in, const int* in_sizes, int n_in,
                              void* d_out, int out_size, void* d_ws, size_t ws_size,
                              hipStream_t stream) {
  const float* node = (const float*)d_in[0];
  const float* edge = (const float*)d_in[1];
  const float* Wn_w = (const float*)d_in[2];
  const float* Wn_b = (const float*)d_in[3];
  const float* Wh_w = (const float*)d_in[4];
  const float* Wh_b = (const float*)d_in[5];
  const float* We_w = (const float*)d_in[6];
  const float* We_b = (const float*)d_in[7];
  const float* Wn2_w = (const float*)d_in[8];
  const float* Wn2_b = (const float*)d_in[9];
  const float* We2_w = (const float*)d_in[10];
  const float* We2_b = (const float*)d_in[11];
  const float* attn_w = (const float*)d_in[12];
  const float* edge_w = (const float*)d_in[13];
  const float* edge_b = (const float*)d_in[14];
  const float* out_n_w = (const float*)d_in[15];
  const float* out_n_b = (const float*)d_in[16];
  const float* out_e_w = (const float*)d_in[17];
  const float* out_e_b = (const float*)d_in[18];

  float* out_node = (float*)d_out;            // 262144
  float* out_edge = ((float*)d_out) + 262144; // 33554432

  float* ws = (float*)d_ws;
  float* node_p = ws;                      // 262144
  float* Whh    = ws + 262144;             // 262144
  float* node_h = ws + 524288;             // 262144
  float* si     = ws + 786432;             // 8192
  float* sjv    = ws + 794624;             // 8192
  float* Pg     = ws + 802816;             // 131072
  float* Qg     = ws + 933888;             // 131072
  float* chg    = ws + 1064960;            // 128
  float* c0g    = ws + 1065088;            // 128
  short* Gt     = (short*)(ws + 1065216);  // 16384 shorts
  float* Vg     = ws + 1073408;            // 1024
  float* seg    = ws + 1074432;            // 2097152

  prep_kernel<<<129, 128, 0, stream>>>(We_w, We_b, attn_w, We2_w, We2_b, edge_w, edge_b,
                                       out_e_w, out_e_b, Vg, chg, c0g, Gt);
  node_in_fused<<<256, 256, 0, stream>>>(node, Wn_w, Wn_b, Wh_w, Wh_b, attn_w, node_p, Whh,
                                         si, sjv);
  se_kernel<<<2048, 256, 0, stream>>>(edge, Vg, chg, seg);
  attn_fused<<<1024, 256, 0, stream>>>(node_p, Whh, si, sjv, seg, node_h);
  node_out_pq<<<256, 256, 0, stream>>>(node_h, out_n_w, out_n_b, Wn2_w, Wn2_b, edge_w,
                                       out_e_w, out_node, Pg, Qg);
  edge_out_kernel<<<1024, 256, 0, stream>>>(edge, Gt, Pg, Qg, c0g, out_e_b, out_edge);
}

// Round 13
// 161.784 us; speedup vs baseline: 1.1456x; 1.0146x over previous
//
#include <hip/hip_runtime.h>

#define Bb 4
#define Ll 256
#define NEG 0.2f

typedef __attribute__((ext_vector_type(8))) short short8;
typedef __attribute__((ext_vector_type(4))) float f32x4;
typedef __attribute__((ext_vector_type(4))) unsigned uint4v;

__device__ __forceinline__ float lrelu(float x) { return x >= 0.f ? x : NEG * x; }

__device__ __forceinline__ short f2bf(float x) {
  unsigned u = __builtin_bit_cast(unsigned, x);
  unsigned r = (u + 0x7FFFu + ((u >> 16) & 1u)) >> 16;
  return (short)r;
}

// pack two f32 -> u32 of 2 bf16 (round half up); elem0 in low 16
__device__ __forceinline__ unsigned pack2bf(float e, float o) {
  unsigned ue = __builtin_bit_cast(unsigned, e);
  unsigned uo = __builtin_bit_cast(unsigned, o);
  return ((ue + 0x8000u) >> 16) | ((uo + 0x8000u) & 0xFFFF0000u);
}

// ---------------- merged prep: blocks 0..127 -> Gt (LINEAR bf16 [n][k]);
// block 128 -> Vg (fp32 [128][8], V[c*8+h]), ch(8), c0(128) ----------------
__global__ void prep_kernel(const float* We_w, const float* We_b, const float* attn_w,
                            const float* We2_w, const float* We2_b, const float* edge_w,
                            const float* edge_b, const float* out_e_w, const float* out_e_b,
                            float* Vg, float* chg, float* c0g, short* Gt) {
  int blk = blockIdx.x;
  int t = threadIdx.x; // 128 threads
  if (blk < 128) {
    __shared__ float m2[128];
    int c = blk; // k index
    int h = t >> 4, e = t & 15;
    float s = 0.f;
    for (int d = 0; d < 16; ++d) s += We2_w[c * 128 + h * 16 + d] * edge_w[d * 16 + e];
    m2[t] = s;
    __syncthreads();
    float g = 0.f;
    for (int f = 0; f < 128; ++f) g += m2[f] * out_e_w[f * 128 + t];
    Gt[t * 128 + c] = f2bf(g);
  } else {
    __shared__ float b2e[128];
    const float* we = attn_w + 64;
    for (int idx = t; idx < 1024; idx += 128) {
      int c = idx >> 3, h = idx & 7;
      float s = 0.f;
      for (int d = 0; d < 16; ++d) s += We_w[c * 128 + h * 16 + d] * we[d];
      Vg[idx] = s; // V[c*8+h]
    }
    if (t < 8) {
      float s = 0.f;
      for (int d = 0; d < 16; ++d) s += We_b[t * 16 + d] * we[d];
      chg[t] = s;
    }
    {
      int h = t >> 4, e = t & 15;
      float s = 0.f;
      for (int d = 0; d < 16; ++d) s += We2_b[h * 16 + d] * edge_w[d * 16 + e];
      b2e[t] = s + edge_b[e];
    }
    __syncthreads();
    float s = out_e_b[t];
    for (int f = 0; f < 128; ++f) s += b2e[f] * out_e_w[f * 128 + t];
    c0g[t] = s;
  }
}

// ---------------- se v3: 32 lanes per row, 1 float4/lane, low VGPR, max occupancy ----
__global__ __launch_bounds__(256) void se_kernel(const float* __restrict__ edge,
                                                 const float* __restrict__ Vg,
                                                 const float* __restrict__ chg,
                                                 float* __restrict__ se) {
  int t = threadIdx.x;
  int l32 = t & 31;
  // each lane owns cols [l32*4, l32*4+4)
  float vreg[4][8];
#pragma unroll
  for (int ci = 0; ci < 4; ++ci)
#pragma unroll
    for (int h = 0; h < 8; ++h) vreg[ci][h] = Vg[(l32 * 4 + ci) * 8 + h];
  int hh = 4 * ((l32 >> 4) & 1) + 2 * ((l32 >> 3) & 1) + ((l32 >> 2) & 1);
  float chv = chg[hh];

  long gid = ((long)blockIdx.x * 256 + t) >> 5; // 32-lane group id
  long ngroups = ((long)gridDim.x * 256) >> 5;
  const long NR = (long)Bb * Ll * Ll;
  for (long row = gid; row < NR; row += ngroups) {
    float4 e = reinterpret_cast<const float4*>(edge + row * 128)[l32];
    float p[8];
#pragma unroll
    for (int h = 0; h < 8; ++h)
      p[h] = e.x * vreg[0][h] + e.y * vreg[1][h] + e.z * vreg[2][h] + e.w * vreg[3][h];
    bool h16 = (l32 & 16) != 0;
    float q[4];
#pragma unroll
    for (int k = 0; k < 4; ++k) {
      float keep = h16 ? p[k + 4] : p[k];
      float send = h16 ? p[k] : p[k + 4];
      q[k] = keep + __shfl_xor(send, 16);
    }
    bool h8 = (l32 & 8) != 0;
    float r2[2];
#pragma unroll
    for (int k = 0; k < 2; ++k) {
      float keep = h8 ? q[k + 2] : q[k];
      float send = h8 ? q[k] : q[k + 2];
      r2[k] = keep + __shfl_xor(send, 8);
    }
    bool h4 = (l32 & 4) != 0;
    float s = (h4 ? r2[1] : r2[0]) + __shfl_xor(h4 ? r2[0] : r2[1], 4);
    s += __shfl_xor(s, 2);
    s += __shfl_xor(s, 1);
    if ((l32 & 3) == 0) se[row * 8 + hh] = s + chv;
  }
}

// ---------------- node_in_fused: node_p = node@Wn + b; Whh; si; sj ----------------
__global__ __launch_bounds__(256) void node_in_fused(
    const float* __restrict__ node, const float* __restrict__ Wn_w,
    const float* __restrict__ Wn_b, const float* __restrict__ Wh_w,
    const float* __restrict__ Wh_b, const float* __restrict__ attn_w,
    float* __restrict__ node_p, float* __restrict__ Whh, float* __restrict__ si,
    float* __restrict__ sj) {
  __shared__ float a[4][256];
  __shared__ float np[4][256];
  int t = threadIdx.x;
  int row0 = blockIdx.x * 4;
  for (int q = t; q < 1024; q += 256) a[q >> 8][q & 255] = node[(long)row0 * 256 + q];
  __syncthreads();
  float acc[4];
  float bvv = Wn_b[t];
#pragma unroll
  for (int r = 0; r < 4; ++r) acc[r] = bvv;
  for (int k = 0; k < 256; ++k) {
    float w = Wn_w[k * 256 + t];
#pragma unroll
    for (int r = 0; r < 4; ++r) acc[r] += a[r][k] * w;
  }
#pragma unroll
  for (int r = 0; r < 4; ++r) {
    node_p[(long)(row0 + r) * 256 + t] = acc[r];
    np[r][t] = acc[r];
  }
  __syncthreads();
  int h = t >> 5, e = t & 31;
  float wb2 = Wh_b[e];
#pragma unroll
  for (int r = 0; r < 4; ++r) {
    float s = wb2;
    for (int d = 0; d < 32; ++d) s += np[r][h * 32 + d] * Wh_w[d * 32 + e];
    Whh[(long)(row0 + r) * 256 + t] = s;
  }
  if (t < 64) {
    int r = t >> 4, idx = t & 15, hh = idx & 7;
    const float* w = attn_w + (idx < 8 ? 0 : 32);
    float s = 0.f;
    for (int d = 0; d < 32; ++d) s += np[r][hh * 32 + d] * w[d];
    ((idx < 8) ? si : sj)[(long)(row0 + r) * 8 + hh] = s;
  }
}

// ---------------- attn: softmax + agg from precomputed seg ----------------
__global__ __launch_bounds__(256) void attn_fused(
    const float* __restrict__ node_p, const float* __restrict__ Whh,
    const float* __restrict__ si, const float* __restrict__ sj,
    const float* __restrict__ seg, float* __restrict__ node_h) {
  __shared__ float sjl[2048];
  __shared__ float sel[2048];
  __shared__ float pl[2048];
  __shared__ float sil[8];
  int t = threadIdx.x, bi = blockIdx.x;
  int b = bi >> 8, i = bi & 255;
  for (int q = t; q < 2048; q += 256) sjl[q] = sj[(long)b * 2048 + q];
  for (int q = t; q < 2048; q += 256) sel[q] = seg[(long)bi * 2048 + q];
  if (t < 8) sil[t] = si[(long)bi * 8 + t];
  __syncthreads();

  int g = t >> 5, l32 = t & 31;
  float sc[8];
  float mx = -1e30f;
#pragma unroll
  for (int m = 0; m < 8; ++m) {
    int k = l32 + 32 * m;
    float v = -1e30f;
    if (k < 255) {
      int jj = k + (k >= i ? 1 : 0);
      v = sil[g] + sjl[jj * 8 + g] + sel[jj * 8 + g];
      v = lrelu(v);
    }
    sc[m] = v;
    mx = fmaxf(mx, v);
  }
#pragma unroll
  for (int d = 16; d >= 1; d >>= 1) mx = fmaxf(mx, __shfl_xor(mx, d));
  float sum = 0.f;
#pragma unroll
  for (int m = 0; m < 8; ++m) {
    int k = l32 + 32 * m;
    float e = (k < 255) ? __expf(sc[m] - mx) : 0.f;
    sc[m] = e;
    sum += e;
  }
#pragma unroll
  for (int d = 16; d >= 1; d >>= 1) sum += __shfl_xor(sum, d);
  float inv = 1.f / sum;
#pragma unroll
  for (int m = 0; m < 8; ++m) {
    int k = l32 + 32 * m;
    if (k < 255) pl[k * 8 + g] = sc[m] * inv;
  }
  __syncthreads();

  int h = g;
  const float* wb = Whh + (long)b * 65536 + t;
  float acc0 = 0.f, acc1 = 0.f;
#pragma unroll 8
  for (int j = 0; j < 256; j += 2) {
    int k0 = (j == 0) ? 254 : (j - 1);
    int k1 = j;
    float w0 = (j == i) ? 0.f : pl[k0 * 8 + h];
    float w1 = (j + 1 == i) ? 0.f : pl[k1 * 8 + h];
    acc0 += w0 * wb[(long)j * 256];
    acc1 += w1 * wb[(long)(j + 1) * 256];
  }
  float acc = acc0 + acc1;
  float np = node_p[(long)bi * 256 + t];
  node_h[(long)bi * 256 + t] = np + lrelu(acc);
}

// ---------------- node_out_pq: out_node; node_p2; P/Q ----------------
__global__ __launch_bounds__(256) void node_out_pq(
    const float* __restrict__ node_h, const float* __restrict__ out_n_w,
    const float* __restrict__ out_n_b, const float* __restrict__ Wn2_w,
    const float* __restrict__ Wn2_b, const float* __restrict__ edge_w,
    const float* __restrict__ out_e_w, float* __restrict__ out_node,
    float* __restrict__ Pg, float* __restrict__ Qg) {
  __shared__ float a[4][256];
  __shared__ float b2[4][256];
  __shared__ float ninj[4][256];
  int t = threadIdx.x;
  int row0 = blockIdx.x * 4;
  for (int q = t; q < 1024; q += 256) a[q >> 8][q & 255] = node_h[(long)row0 * 256 + q];
  __syncthreads();
  float acc[4];
  float bv1 = out_n_b[t];
#pragma unroll
  for (int r = 0; r < 4; ++r) acc[r] = bv1;
  for (int k = 0; k < 256; ++k) {
    float w = out_n_w[k * 256 + t];
#pragma unroll
    for (int r = 0; r < 4; ++r) acc[r] += a[r][k] * w;
  }
#pragma unroll
  for (int r = 0; r < 4; ++r) {
    out_node[(long)(row0 + r) * 256 + t] = acc[r];
    b2[r][t] = acc[r];
  }
  __syncthreads();
  float acc2[4];
  float bv2 = Wn2_b[t];
#pragma unroll
  for (int r = 0; r < 4; ++r) acc2[r] = bv2;
  for (int k = 0; k < 256; ++k) {
    float w = Wn2_w[k * 256 + t];
#pragma unroll
    for (int r = 0; r < 4; ++r) acc2[r] += b2[r][k] * w;
  }
#pragma unroll
  for (int r = 0; r < 4; ++r) a[r][t] = acc2[r]; // node_p2
  __syncthreads();
  {
    int f = t & 127, h = f >> 4, e = f & 15;
    const float* w = edge_w + 256 + (t >> 7) * 512; // w_i / w_j
#pragma unroll
    for (int r = 0; r < 4; ++r) {
      float s = 0.f;
      for (int d = 0; d < 32; ++d) s += a[r][h * 32 + d] * w[d * 16 + e];
      ninj[r][t] = s;
    }
  }
  __syncthreads();
  {
    int o = t & 127;
    int half = (t >> 7) * 128;
#pragma unroll
    for (int r = 0; r < 4; ++r) {
      float s = 0.f;
      const float* src = ninj[r] + half;
      for (int f = 0; f < 128; ++f) s += src[f] * out_e_w[f * 128 + o];
      ((t < 128) ? Pg : Qg)[(long)(row0 + r) * 128 + o] = s;
    }
  }
}

// ---------------- edge_out v8: persistent blocks, gload_lds staging, counted-vmcnt
// pipeline (raw s_barrier, no mid-loop drain). 1024 blocks x 8 tiles of 32x128.
// Wave = 16 rows x 64 cols. D[row=lq*4+r][col=nf*16+lc] (v7-verified mapping).
#define TPB_E 8
__global__ __launch_bounds__(256, 3) void edge_out_kernel(
    const float* __restrict__ edge, const short* __restrict__ Gt,
    const float* __restrict__ Pg, const float* __restrict__ Qg,
    const float* __restrict__ c0g, const float* __restrict__ oeb,
    float* __restrict__ out_edge) {
  __shared__ __align__(16) float abuf[2][32 * 128]; // 2 x 16 KB, row-swizzled image
  int t = threadIdx.x;
  int l = t & 63, wid = t >> 6;
  int wm = wid >> 1, wn = wid & 1;
  int lc = l & 15, lq = l >> 4;

  // G fragments in registers (linear Gt)
  short8 bv[4][4];
#pragma unroll
  for (int ks = 0; ks < 4; ++ks)
#pragma unroll
    for (int nf = 0; nf < 4; ++nf)
      bv[ks][nf] = *(const short8*)(Gt + (wn * 64 + nf * 16 + lc) * 128 + ks * 32 + lq * 8);

  float oebv[4];
#pragma unroll
  for (int nf = 0; nf < 4; ++nf) oebv[nf] = oeb[wn * 64 + nf * 16 + lc];

  long tile0 = (long)blockIdx.x * TPB_E;

  auto stage = [&](int buf, long tile) {
#pragma unroll
    for (int q = 0; q < 4; ++q) {
      int L = q * 256 + t; // 16B chunk index
      int row = L >> 5, c4 = L & 31;
      int scol = (c4 * 4) ^ ((row & 7) << 2); // float index within row
      const float* gp = edge + (tile * 32 + row) * 128 + scol;
      char* lp = (char*)abuf[buf] + q * 4096 + wid * 1024;
      __builtin_amdgcn_global_load_lds(
          (const __attribute__((address_space(1))) unsigned*)gp,
          (__attribute__((address_space(3))) unsigned*)lp, 16, 0, 0);
    }
  };

  stage(0, tile0);
  __syncthreads(); // prologue: full drain once

  int cur = 0;
  for (int tt = 0; tt < TPB_E; ++tt) {
    long tile = tile0 + tt;
    if (tt + 1 < TPB_E) stage(cur ^ 1, tile + 1);

    int bi = (int)(tile >> 3);
    int b = bi >> 8, i = bi & 255;
    int row0loc = (int)(tile & 7) * 32;

    float pcv[4];
#pragma unroll
    for (int nf = 0; nf < 4; ++nf) {
      int col = wn * 64 + nf * 16 + lc;
      pcv[nf] = Pg[(long)bi * 128 + col] + c0g[col];
    }

    const char* rbase = (const char*)abuf[cur] + (wm * 16 + lc) * 512;
    int sw = ((wm * 16 + lc) & 7) << 4;

    f32x4 acc[4];
#pragma unroll
    for (int nf = 0; nf < 4; ++nf) acc[nf] = (f32x4){0.f, 0.f, 0.f, 0.f};
#pragma unroll
    for (int ks = 0; ks < 4; ++ks) {
      int cb = ks * 128 + lq * 32;
      float4 f0 = *(const float4*)(rbase + (cb ^ sw));
      float4 f1 = *(const float4*)(rbase + ((cb + 16) ^ sw));
      uint4v u;
      u.x = pack2bf(f0.x, f0.y);
      u.y = pack2bf(f0.z, f0.w);
      u.z = pack2bf(f1.x, f1.y);
      u.w = pack2bf(f1.z, f1.w);
      short8 av = __builtin_bit_cast(short8, u);
#pragma unroll
      for (int nf = 0; nf < 4; ++nf)
        acc[nf] = __builtin_amdgcn_mfma_f32_16x16x32_bf16(av, bv[ks][nf], acc[nf], 0, 0, 0);
    }

#pragma unroll
    for (int r = 0; r < 4; ++r) {
      int jloc = row0loc + wm * 16 + lq * 4 + r;
      float* orow = out_edge + ((long)bi * 256 + jloc) * 128;
      const float* Qrow = Qg + (long)(b * 256 + jloc) * 128;
      bool diag = (jloc == i);
#pragma unroll
      for (int nf = 0; nf < 4; ++nf) {
        int col = wn * 64 + nf * 16 + lc;
        float v = diag ? oebv[nf] : (acc[nf][r] + pcv[nf] + Qrow[col]);
        orow[col] = v;
      }
    }

    asm volatile("s_waitcnt vmcnt(16)" ::: "memory");
    __builtin_amdgcn_s_barrier();
    asm volatile("" ::: "memory");
    cur ^= 1;
  }
}

extern "C" void kernel_launch(void* const* d_in, const int* in_sizes, int n_in,
                              void* d_out, int out_size, void* d_ws, size_t ws_size,
                              hipStream_t stream) {
  const float* node = (const float*)d_in[0];
  const float* edge = (const float*)d_in[1];
  const float* Wn_w = (const float*)d_in[2];
  const float* Wn_b = (const float*)d_in[3];
  const float* Wh_w = (const float*)d_in[4];
  const float* Wh_b = (const float*)d_in[5];
  const float* We_w = (const float*)d_in[6];
  const float* We_b = (const float*)d_in[7];
  const float* Wn2_w = (const float*)d_in[8];
  const float* Wn2_b = (const float*)d_in[9];
  const float* We2_w = (const float*)d_in[10];
  const float* We2_b = (const float*)d_in[11];
  const float* attn_w = (const float*)d_in[12];
  const float* edge_w = (const float*)d_in[13];
  const float* edge_b = (const float*)d_in[14];
  const float* out_n_w = (const float*)d_in[15];
  const float* out_n_b = (const float*)d_in[16];
  const float* out_e_w = (const float*)d_in[17];
  const float* out_e_b = (const float*)d_in[18];

  float* out_node = (float*)d_out;            // 262144
  float* out_edge = ((float*)d_out) + 262144; // 33554432

  float* ws = (float*)d_ws;
  float* node_p = ws;                      // 262144
  float* Whh    = ws + 262144;             // 262144
  float* node_h = ws + 524288;             // 262144
  float* si     = ws + 786432;             // 8192
  float* sjv    = ws + 794624;             // 8192
  float* Pg     = ws + 802816;             // 131072
  float* Qg     = ws + 933888;             // 131072
  float* chg    = ws + 1064960;            // 128
  float* c0g    = ws + 1065088;            // 128
  short* Gt     = (short*)(ws + 1065216);  // 16384 shorts
  float* Vg     = ws + 1073408;            // 1024
  float* seg    = ws + 1074432;            // 2097152

  prep_kernel<<<129, 128, 0, stream>>>(We_w, We_b, attn_w, We2_w, We2_b, edge_w, edge_b,
                                       out_e_w, out_e_b, Vg, chg, c0g, Gt);
  node_in_fused<<<256, 256, 0, stream>>>(node, Wn_w, Wn_b, Wh_w, Wh_b, attn_w, node_p, Whh,
                                         si, sjv);
  se_kernel<<<2048, 256, 0, stream>>>(edge, Vg, chg, seg);
  attn_fused<<<1024, 256, 0, stream>>>(node_p, Whh, si, sjv, seg, node_h);
  node_out_pq<<<256, 256, 0, stream>>>(node_h, out_n_w, out_n_b, Wn2_w, Wn2_b, edge_w,
                                       out_e_w, out_node, Pg, Qg);
  edge_out_kernel<<<1024, 256, 0, stream>>>(edge, Gt, Pg, Qg, c0g, out_e_b, out_edge);
}